// Round 2
// baseline (28947.311 us; speedup 1.0000x reference)
//
#include <hip/hip_runtime.h>
#include <hip/hip_cooperative_groups.h>
#include <math.h>

namespace cg = cooperative_groups;

constexpr int nB = 64, nS = 256, nAc = 256, nH = 512, nG = 2048;
constexpr int nWD = 320, nNA = 75, nLB = 48, nFH = 2560;
constexpr int BH = nB * nH; // 32768

typedef _Float16 h16;
typedef _Float16 h16x8 __attribute__((ext_vector_type(8)));
typedef _Float16 h16x4 __attribute__((ext_vector_type(4)));

__device__ __forceinline__ float sigf(float x) { return 1.0f / (1.0f + __expf(-x)); }

// ---------------- init: zero hsrec prefix (fp16) + sort counters ----------------
__global__ void init_k(h16* __restrict__ hsrec, int* __restrict__ counts, int* __restrict__ fill)
{
    int i = blockIdx.x * 256 + threadIdx.x;
    if (i < 2 * BH) hsrec[i] = (h16)0.0f;
    if (i < nLB) { counts[i] = 0; fill[i] = 0; }
}

// ---------------- embedding gather -> tok fp16 [b][s][0:320] ----------------
__global__ __launch_bounds__(64)
void embed_k(const int* __restrict__ tokb, const int* __restrict__ posb,
             const float* __restrict__ wemb, const float* __restrict__ pemb,
             h16* __restrict__ tok)
{
    const int r = blockIdx.x;            // b*nS + s
    const int tid = threadIdx.x;
    const int tk = tokb[r], pp = posb[r];
    h16x8* d = (h16x8*)(tok + (size_t)r * nWD);
    if (tid < 32) {
        const float4* sw = (const float4*)(wemb + (size_t)tk * 256);
        const float4 a = sw[2 * tid], b = sw[2 * tid + 1];
        h16x8 o;
        o[0]=(h16)a.x; o[1]=(h16)a.y; o[2]=(h16)a.z; o[3]=(h16)a.w;
        o[4]=(h16)b.x; o[5]=(h16)b.y; o[6]=(h16)b.z; o[7]=(h16)b.w;
        d[tid] = o;
    } else if (tid < 40) {
        const int q = tid - 32;
        const float4* sp = (const float4*)(pemb + (size_t)pp * 64);
        const float4 a = sp[2 * q], b = sp[2 * q + 1];
        h16x8 o;
        o[0]=(h16)a.x; o[1]=(h16)a.y; o[2]=(h16)a.z; o[3]=(h16)a.w;
        o[4]=(h16)b.x; o[5]=(h16)b.y; o[6]=(h16)b.z; o[7]=(h16)b.w;
        d[32 + q] = o;
    }
}

// ---------------- action-gate table: acTab[a][j] = aemb[a]·aWih[j] + ab[j] ----------------
__global__ __launch_bounds__(256)
void actab_k(const float* __restrict__ aemb, const float* __restrict__ aWih,
             const float* __restrict__ ab, float* __restrict__ acTab)
{
    const int a = blockIdx.x;            // 0..74
    __shared__ float ae[64];
    const int tid = threadIdx.x;
    if (tid < 64) ae[tid] = aemb[a * 64 + tid];
    __syncthreads();
    for (int j = tid; j < nG; j += 256) {
        const float* wr = aWih + (size_t)j * 64;
        float s = ab[j];
        #pragma unroll
        for (int k = 0; k < 64; k += 4) {
            const float4 w = *(const float4*)(wr + k);
            s = fmaf(w.x, ae[k], s);     s = fmaf(w.y, ae[k + 1], s);
            s = fmaf(w.z, ae[k + 2], s); s = fmaf(w.w, ae[k + 3], s);
        }
        acTab[(size_t)a * nG + j] = s;
    }
}

// ---------------- fp16-in / fp16-out GEMM: C[r][n] = Arow(r)·Wm[n][:] + bias[n] ----------------
// MODE 0: A=tok fp16, r=(s*64+b) -> tok[(b*nS+s)*nWD]     (tokX)
// MODE 1: A=stin fp16, row r*nH                            (stX)
// MODE 3: A pieces hsrec+2BH, hsrec+BH, hsrec, tokrec, harec (hidden, RELU)
// MODE 4: A=composed fp16 row r*nWD, epilogue += tokrec    (st_in)
template<int MODE, bool RELU>
__global__ __launch_bounds__(256)
void gemm_k(const float* __restrict__ Wm, const float* __restrict__ bias,
            const h16* __restrict__ A0, const h16* __restrict__ A1,
            const h16* __restrict__ A2, h16* __restrict__ C, int Ktot, int ldC)
{
    const int bm = blockIdx.x << 6, bn = blockIdx.y << 6;
    const int tid = threadIdx.x;
    const int alm = tid >> 1, alk = (tid & 1) << 3;     // A: 128 threads x 8 halfs
    const int wlm = tid >> 2, wlk = (tid & 3) << 2;     // W: 256 threads x float4
    const int trow = tid >> 4, tcol = tid & 15;
    __shared__ __align__(16) float As[16][68];
    __shared__ __align__(16) float Ws[16][68];
    const int r = bm + alm;
    const h16* arow = nullptr;
    if (MODE == 0) { const int b = r & 63, s = r >> 6; arow = A0 + ((size_t)b * nS + s) * nWD; }
    if (MODE == 1) { arow = A0 + (size_t)r * nH; }
    if (MODE == 4) { arow = A0 + (size_t)r * nWD; }
    const float* wrow = Wm + (size_t)(bn + wlm) * Ktot;
    float acc[4][4] = {};
    for (int k0 = 0; k0 < Ktot; k0 += 16) {
        h16x8 av;
        if (tid < 128) {
            if (MODE == 3) {
                const int p = k0 >> 9;
                const h16* base = (p == 0) ? A0 + 2 * BH : (p == 1) ? A0 + BH
                                : (p == 2) ? A0 : (p == 3) ? A1 : A2;
                av = *(const h16x8*)(base + (size_t)r * nH + (k0 & 511) + alk);
            } else {
                av = *(const h16x8*)(arow + k0 + alk);
            }
        }
        const float4 wv = *(const float4*)(wrow + k0 + wlk);
        __syncthreads();
        if (tid < 128) {
            #pragma unroll
            for (int j = 0; j < 8; ++j) As[alk + j][alm] = (float)av[j];
        }
        Ws[wlk + 0][wlm] = wv.x; Ws[wlk + 1][wlm] = wv.y;
        Ws[wlk + 2][wlm] = wv.z; Ws[wlk + 3][wlm] = wv.w;
        __syncthreads();
        #pragma unroll
        for (int kk = 0; kk < 16; ++kk) {
            const float4 a4 = *(const float4*)&As[kk][trow << 2];
            const float4 w4 = *(const float4*)&Ws[kk][tcol << 2];
            const float aa[4] = {a4.x, a4.y, a4.z, a4.w};
            const float ww[4] = {w4.x, w4.y, w4.z, w4.w};
            #pragma unroll
            for (int i = 0; i < 4; ++i)
                #pragma unroll
                for (int j = 0; j < 4; ++j)
                    acc[i][j] = fmaf(aa[i], ww[j], acc[i][j]);
        }
    }
    #pragma unroll
    for (int i = 0; i < 4; ++i) {
        const int rr = bm + (trow << 2) + i;
        const int cc = bn + (tcol << 2);
        h16x4 v;
        #pragma unroll
        for (int j = 0; j < 4; ++j) {
            float x = acc[i][j] + bias[cc + j];
            if (MODE == 4) x += (float)A1[(size_t)rr * nH + cc + j];
            if (RELU) x = fmaxf(x, 0.0f);
            v[j] = (h16)x;
        }
        *(h16x4*)(C + (size_t)rr * ldC + cc) = v;
    }
}

// ---------------- label sort for red_W batched GEMM ----------------
__global__ void hist_k(const int* __restrict__ actb, int* __restrict__ lab, int* __restrict__ counts)
{
    const int r = blockIdx.x * 256 + threadIdx.x;   // r = t*64+b
    const int t = r >> 6, b = r & 63;
    const int a = actb[b * nAc + t];
    const int l = a % nLB;
    lab[r] = l;
    atomicAdd(&counts[l], 1);
}

__global__ void tiles_k(const int* __restrict__ counts, int* __restrict__ offs,
                        int* __restrict__ tl_lab, int* __restrict__ tl_start,
                        int* __restrict__ tl_cnt, int* __restrict__ ntiles)
{
    if (blockIdx.x == 0 && threadIdx.x == 0) {
        int o = 0, nt = 0;
        for (int l = 0; l < nLB; ++l) {
            offs[l] = o;
            const int c = counts[l];
            for (int s0 = 0; s0 < c; s0 += 64) {
                tl_lab[nt] = l; tl_start[nt] = o + s0; tl_cnt[nt] = min(64, c - s0); ++nt;
            }
            o += c;
        }
        offs[nLB] = o;
        ntiles[0] = nt;
    }
}

__global__ void scatter_k(const int* __restrict__ lab, const int* __restrict__ offs,
                          int* __restrict__ fill, int* __restrict__ idx)
{
    const int r = blockIdx.x * 256 + threadIdx.x;
    const int l = lab[r];
    const int pos = offs[l] + atomicAdd(&fill[l], 1);
    idx[pos] = r;
}

// composed[r][i] = tanh( pair(r)·red_W[l][i][:] + red_b[l][i] ), rows grouped by label
__global__ __launch_bounds__(256)
void comp_gemm_k(const h16* __restrict__ tok, const float* __restrict__ redW,
                 const float* __restrict__ redb, const int* __restrict__ idx,
                 const int* __restrict__ tl_lab, const int* __restrict__ tl_start,
                 const int* __restrict__ tl_cnt, const int* __restrict__ ntiles,
                 h16* __restrict__ comp)
{
    const int tile = blockIdx.x;
    if (tile >= ntiles[0]) return;
    const int cn0 = blockIdx.y << 6;
    const int l = tl_lab[tile], rst = tl_start[tile], mrows = tl_cnt[tile];
    __shared__ int rows_s[64];
    __shared__ __align__(16) float As[16][68];
    __shared__ __align__(16) float Ws[16][68];
    const int tid = threadIdx.x;
    if (tid < 64) rows_s[tid] = (tid < mrows) ? idx[rst + tid] : -1;
    __syncthreads();
    const int alm = tid >> 1, alk = (tid & 1) << 3;
    const int wlm = tid >> 2, wlk = (tid & 3) << 2;
    const int trow = tid >> 4, tcol = tid & 15;
    const int rm = (tid < 128) ? rows_s[alm] : -1;
    const h16* arow0 = tok;
    const h16* arow1 = tok;
    if (rm >= 0) {
        const int b = rm & 63, t = rm >> 6;
        arow0 = tok + ((size_t)b * nS + t) * nWD;
        arow1 = tok + ((size_t)b * nS + max(t - 1, 0)) * nWD;
    }
    const float* wrow = redW + (size_t)l * (320 * 640) + (size_t)(cn0 + wlm) * 640;
    float acc[4][4] = {};
    for (int k0 = 0; k0 < 640; k0 += 16) {
        const int k = k0 + alk;
        h16x8 av = {};
        if (rm >= 0) av = (k < 320) ? *(const h16x8*)(arow0 + k)
                                    : *(const h16x8*)(arow1 + (k - 320));
        const float4 wv = *(const float4*)(wrow + k0 + wlk);
        __syncthreads();
        if (tid < 128) {
            #pragma unroll
            for (int j = 0; j < 8; ++j) As[alk + j][alm] = (float)av[j];
        }
        Ws[wlk + 0][wlm] = wv.x; Ws[wlk + 1][wlm] = wv.y;
        Ws[wlk + 2][wlm] = wv.z; Ws[wlk + 3][wlm] = wv.w;
        __syncthreads();
        #pragma unroll
        for (int kk = 0; kk < 16; ++kk) {
            const float4 a4 = *(const float4*)&As[kk][trow << 2];
            const float4 w4 = *(const float4*)&Ws[kk][tcol << 2];
            const float aa[4] = {a4.x, a4.y, a4.z, a4.w};
            const float ww[4] = {w4.x, w4.y, w4.z, w4.w};
            #pragma unroll
            for (int i = 0; i < 4; ++i)
                #pragma unroll
                for (int j = 0; j < 4; ++j)
                    acc[i][j] = fmaf(aa[i], ww[j], acc[i][j]);
        }
    }
    #pragma unroll
    for (int i = 0; i < 4; ++i) {
        const int rr = rows_s[(trow << 2) + i];
        if (rr < 0) continue;
        #pragma unroll
        for (int j = 0; j < 4; ++j) {
            const int cc = cn0 + (tcol << 2) + j;
            comp[(size_t)rr * nWD + cc] = (h16)tanhf(acc[i][j] + redb[l * nWD + cc]);
        }
    }
}

// ---------------- token LSTM scan (cooperative, 256 blocks x 512 thr) ----------------
__global__ __launch_bounds__(512)
void tok_scan_k(const float* __restrict__ Whh, const h16* __restrict__ gx,
                float* __restrict__ hbuf, float* __restrict__ cst,
                h16* __restrict__ tokrec)
{
    cg::grid_group grid = cg::this_grid();
    const int blk = blockIdx.x;
    const int g = blk >> 5, jb = blk & 31;
    const int tid = threadIdx.x;
    const int kg = tid & 7, r64 = tid >> 3;
    const int c = r64 >> 4, jl = r64 & 15;
    const int grow = c * nH + (jb << 4) + jl;
    const float* wrow = Whh + (size_t)grow * nH;
    const int r64u = tid & 63, bu = tid >> 6;
    const int grow_u = (r64u >> 4) * nH + (jb << 4) + (r64u & 15);
    __shared__ __align__(16) float hsm[8][nH];
    __shared__ float ps[8][8][65];
    __shared__ float gex[64][9];
    for (int t = 0; t < nS; ++t) {
        if (t == 0) {
            for (int i = tid; i < 8 * nH; i += 512) ((float*)hsm)[i] = 0.0f;
        } else {
            const float4* src = (const float4*)(hbuf + (size_t)((t - 1) & 1) * BH + (g << 3) * nH);
            float4* dst = (float4*)hsm;
            #pragma unroll
            for (int i2 = 0; i2 < 2; ++i2) dst[tid + i2 * 512] = src[tid + i2 * 512];
        }
        __syncthreads();
        const float gxv = (float)gx[(size_t)((t << 6) + (g << 3) + bu) * nG + grow_u];
        float acc[8] = {0.f,0.f,0.f,0.f,0.f,0.f,0.f,0.f};
        #pragma unroll 4
        for (int i = 0; i < 16; ++i) {
            const int k = (i << 5) + (kg << 2);
            const float4 wv = *(const float4*)(wrow + k);
            #pragma unroll
            for (int b = 0; b < 8; ++b) {
                const float4 hv = *(const float4*)(&hsm[b][k]);
                acc[b] = fmaf(wv.x, hv.x, acc[b]);
                acc[b] = fmaf(wv.y, hv.y, acc[b]);
                acc[b] = fmaf(wv.z, hv.z, acc[b]);
                acc[b] = fmaf(wv.w, hv.w, acc[b]);
            }
        }
        #pragma unroll
        for (int b = 0; b < 8; ++b) ps[kg][b][r64] = acc[b];
        __syncthreads();
        float gsum = gxv;
        #pragma unroll
        for (int k2 = 0; k2 < 8; ++k2) gsum += ps[k2][bu][r64u];
        gex[r64u][bu] = gsum;
        __syncthreads();
        if (tid < 128) {
            const int jl2 = tid >> 3, b2 = tid & 7;
            const float gi = gex[jl2][b2];
            const float gf = gex[16 + jl2][b2];
            const float gg = gex[32 + jl2][b2];
            const float go = gex[48 + jl2][b2];
            const int bg = (g << 3) + b2, jh = (jb << 4) + jl2;
            const float cold = (t == 0) ? 0.0f : cst[bg * nH + jh];
            const float cn = sigf(gf) * cold + sigf(gi) * tanhf(gg);
            const float hn = sigf(go) * tanhf(cn);
            cst[bg * nH + jh] = cn;
            hbuf[(size_t)(t & 1) * BH + bg * nH + jh] = hn;
            tokrec[(size_t)t * BH + bg * nH + jh] = (h16)hn;
        }
        grid.sync();
    }
}

// ---------------- action scan: two independent LSTM chains (512 blocks x 256 thr) ----------------
__global__ __launch_bounds__(256)
void act_scan_k(const float* __restrict__ sWhh, const float* __restrict__ aWhh,
                const h16* __restrict__ stX, const float* __restrict__ acTab,
                const int* __restrict__ actb,
                float* __restrict__ spbuf, float* __restrict__ apbuf,
                float* __restrict__ cs_st, float* __restrict__ cs_ac,
                h16* __restrict__ hsrec, h16* __restrict__ harec)
{
    cg::grid_group grid = cg::this_grid();
    const int blk = blockIdx.x;
    const int role = blk >> 8;              // 0 = stack LSTM, 1 = action LSTM
    const int sub = blk & 255;
    const int g = sub >> 5, jb = sub & 31;
    const int tid = threadIdx.x;
    const int kg = tid & 3, r64 = tid >> 2;
    const int c = r64 >> 4, jl = r64 & 15;
    const int grow = c * nH + (jb << 4) + jl;
    const float* Whh = role ? aWhh : sWhh;
    float* cbuf      = role ? cs_ac : cs_st;
    float* pbuf      = role ? apbuf : spbuf;
    const float* wrow = Whh + (size_t)grow * nH;
    const int r64u = tid & 63, bu0 = (tid >> 6) << 1;
    const int grow_u = (r64u >> 4) * nH + (jb << 4) + (r64u & 15);
    __shared__ __align__(16) float hsm[8][nH];
    __shared__ float ps[4][8][65];
    __shared__ float gex[64][9];
    __shared__ int aidx[8];
    for (int t = 0; t < nAc; ++t) {
        if (t == 0) {
            for (int i = tid; i < 8 * nH; i += 256) ((float*)hsm)[i] = 0.0f;
        } else {
            const float4* src = (const float4*)(pbuf + (size_t)((t - 1) & 1) * BH + (g << 3) * nH);
            float4* dst = (float4*)hsm;
            #pragma unroll
            for (int i2 = 0; i2 < 4; ++i2) dst[tid + i2 * 256] = src[tid + i2 * 256];
        }
        if (role && tid < 8) aidx[tid] = actb[((g << 3) + tid) * nAc + t];
        __syncthreads();
        float gpre[2];
        #pragma unroll
        for (int bb = 0; bb < 2; ++bb) {
            if (role) gpre[bb] = acTab[(size_t)aidx[bu0 + bb] * nG + grow_u];
            else      gpre[bb] = (float)stX[(size_t)((t << 6) + (g << 3) + bu0 + bb) * nG + grow_u];
        }
        float acc[8] = {0.f,0.f,0.f,0.f,0.f,0.f,0.f,0.f};
        #pragma unroll 4
        for (int i = 0; i < 32; ++i) {
            const int k = (i << 4) + (kg << 2);
            const float4 wv = *(const float4*)(wrow + k);
            #pragma unroll
            for (int b = 0; b < 8; ++b) {
                const float4 hv = *(const float4*)(&hsm[b][k]);
                acc[b] = fmaf(wv.x, hv.x, acc[b]);
                acc[b] = fmaf(wv.y, hv.y, acc[b]);
                acc[b] = fmaf(wv.z, hv.z, acc[b]);
                acc[b] = fmaf(wv.w, hv.w, acc[b]);
            }
        }
        #pragma unroll
        for (int b = 0; b < 8; ++b) ps[kg][b][r64] = acc[b];
        __syncthreads();
        #pragma unroll
        for (int bb = 0; bb < 2; ++bb) {
            float gsum = gpre[bb];
            #pragma unroll
            for (int k2 = 0; k2 < 4; ++k2) gsum += ps[k2][bu0 + bb][r64u];
            gex[r64u][bu0 + bb] = gsum;
        }
        __syncthreads();
        if (tid < 128) {
            const int jl2 = tid >> 3, b2 = tid & 7;
            const float gi = gex[jl2][b2];
            const float gf = gex[16 + jl2][b2];
            const float gg = gex[32 + jl2][b2];
            const float go = gex[48 + jl2][b2];
            const int bg = (g << 3) + b2, jh = (jb << 4) + jl2;
            const float cold = (t == 0) ? 0.0f : cbuf[bg * nH + jh];
            const float cn = sigf(gf) * cold + sigf(gi) * tanhf(gg);
            const float hn = sigf(go) * tanhf(cn);
            cbuf[bg * nH + jh] = cn;
            pbuf[(size_t)(t & 1) * BH + bg * nH + jh] = hn;
            if (role) harec[(size_t)t * BH + bg * nH + jh] = (h16)hn;
            else      hsrec[(size_t)(t + 2) * BH + bg * nH + jh] = (h16)hn;
        }
        grid.sync();
    }
}

// ---------------- per-(t,b) logits + log-softmax loss ----------------
__global__ __launch_bounds__(128)
void loss_k(const h16* __restrict__ hidden, const float* __restrict__ f2aW,
            const float* __restrict__ f2ab, const int* __restrict__ actb,
            float* __restrict__ losses)
{
    const int r = blockIdx.x;
    const int t = r >> 6, b = r & 63;
    __shared__ __align__(16) float hrow[nH];
    __shared__ float lg[nNA + 1];
    const int tid = threadIdx.x;
    if (tid < 64) {
        const h16x8 v = ((const h16x8*)(hidden + (size_t)r * nH))[tid];
        #pragma unroll
        for (int j = 0; j < 8; ++j) hrow[tid * 8 + j] = (float)v[j];
    }
    __syncthreads();
    if (tid < nNA) {
        const float* wr = f2aW + (size_t)tid * nH;
        float a = f2ab[tid];
        for (int k = 0; k < nH; k += 4) {
            const float4 wv = *(const float4*)(wr + k);
            const float4 hv = *(const float4*)(&hrow[k]);
            a = fmaf(wv.x, hv.x, a); a = fmaf(wv.y, hv.y, a);
            a = fmaf(wv.z, hv.z, a); a = fmaf(wv.w, hv.w, a);
        }
        lg[tid] = a;
    }
    __syncthreads();
    if (tid < 64) {
        float m = -1e30f;
        for (int i = tid; i < nNA; i += 64) m = fmaxf(m, lg[i]);
        #pragma unroll
        for (int o = 32; o > 0; o >>= 1) m = fmaxf(m, __shfl_xor(m, o));
        float s = 0.0f;
        for (int i = tid; i < nNA; i += 64) s += __expf(lg[i] - m);
        #pragma unroll
        for (int o = 32; o > 0; o >>= 1) s += __shfl_xor(s, o);
        if (tid == 0) {
            const int a = actb[b * nAc + t];
            losses[r] = m + logf(s) - lg[a];
        }
    }
}

__global__ __launch_bounds__(256)
void reduce_k(const float* __restrict__ losses, float* __restrict__ out)
{
    __shared__ float sm[256];
    const int tid = threadIdx.x;
    float a = 0.0f;
    for (int i = tid; i < nS * nB; i += 256) a += losses[i];
    sm[tid] = a; __syncthreads();
    for (int s = 128; s > 0; s >>= 1) { if (tid < s) sm[tid] += sm[tid + s]; __syncthreads(); }
    if (tid == 0) out[0] = sm[0] * (1.0f / 16384.0f);
}

// ---------------- launch ----------------
extern "C" void kernel_launch(void* const* d_in, const int* in_sizes, int n_in,
                              void* d_out, int out_size, void* d_ws, size_t ws_size,
                              hipStream_t stream)
{
    const int*   tokb  = (const int*)  d_in[0];
    const int*   posb  = (const int*)  d_in[1];
    const int*   actb  = (const int*)  d_in[3];
    const float* wemb  = (const float*)d_in[4];
    const float* pemb  = (const float*)d_in[5];
    const float* aemb  = (const float*)d_in[6];
    const float* tWih  = (const float*)d_in[7];
    const float* tWhh  = (const float*)d_in[8];
    const float* tb    = (const float*)d_in[9];
    const float* sWih  = (const float*)d_in[10];
    const float* sWhh  = (const float*)d_in[11];
    const float* sb    = (const float*)d_in[12];
    const float* aWih  = (const float*)d_in[13];
    const float* aWhh  = (const float*)d_in[14];
    const float* ab    = (const float*)d_in[15];
    const float* redW  = (const float*)d_in[16];
    const float* redb  = (const float*)d_in[17];
    const float* compW = (const float*)d_in[18];
    const float* compb = (const float*)d_in[19];
    const float* h2fW  = (const float*)d_in[20];
    const float* h2fb  = (const float*)d_in[21];
    const float* f2aW  = (const float*)d_in[22];
    const float* f2ab  = (const float*)d_in[23];

    // ---- workspace carve (~123 MB total) ----
    char* base = (char*)d_ws;
    auto carve = [&](size_t bytes) { char* p = base; base += (bytes + 255) & ~(size_t)255; return p; };
    h16*   tok    = (h16*)  carve((size_t)nB * nS * nWD * 2);        // 10.5 MB
    h16*   Xh     = (h16*)  carve((size_t)nS * nB * nG * 2);         // 32 MB (tokX -> stX -> hidden)
    h16*   comph  = (h16*)  carve((size_t)nS * nB * nWD * 2);        // 10.5 MB
    h16*   stinh  = (h16*)  carve((size_t)nS * BH * 2);              // 16 MB
    h16*   tokrec = (h16*)  carve((size_t)nS * BH * 2);              // 16 MB
    h16*   hsrec  = (h16*)  carve((size_t)(nS + 2) * BH * 2);        // 16.9 MB
    h16*   harec  = (h16*)  carve((size_t)nS * BH * 2);              // 16 MB
    float* acTab  = (float*)carve((size_t)nNA * nG * 4);             // 0.6 MB
    float* hbuf   = (float*)carve((size_t)2 * BH * 4);
    float* spbuf  = (float*)carve((size_t)2 * BH * 4);
    float* apbuf  = (float*)carve((size_t)2 * BH * 4);
    float* cst    = (float*)carve((size_t)BH * 4);
    float* cs_st  = (float*)carve((size_t)BH * 4);
    float* cs_ac  = (float*)carve((size_t)BH * 4);
    float* losses = (float*)carve((size_t)nS * nB * 4);
    int*   lab      = (int*)carve((size_t)nS * nB * 4);
    int*   counts   = (int*)carve(nLB * 4);
    int*   offs     = (int*)carve((nLB + 1) * 4);
    int*   fill     = (int*)carve(nLB * 4);
    int*   tl_lab   = (int*)carve(320 * 4);
    int*   tl_start = (int*)carve(320 * 4);
    int*   tl_cnt   = (int*)carve(320 * 4);
    int*   ntiles   = (int*)carve(4);
    int*   idxb     = (int*)carve((size_t)nS * nB * 4);

    init_k<<<dim3(256), dim3(256), 0, stream>>>(hsrec, counts, fill);
    embed_k<<<dim3(nB * nS), dim3(64), 0, stream>>>(tokb, posb, wemb, pemb, tok);
    actab_k<<<dim3(nNA), dim3(256), 0, stream>>>(aemb, aWih, ab, acTab);
    // tokX = tok @ tok_Wih.T + tok_b  -> Xh
    gemm_k<0,false><<<dim3(256, 32), dim3(256), 0, stream>>>(tWih, tb, tok, nullptr, nullptr, Xh, nWD, nG);
    // label sort + composed
    hist_k<<<dim3(64), dim3(256), 0, stream>>>(actb, lab, counts);
    tiles_k<<<dim3(1), dim3(64), 0, stream>>>(counts, offs, tl_lab, tl_start, tl_cnt, ntiles);
    scatter_k<<<dim3(64), dim3(256), 0, stream>>>(lab, offs, fill, idxb);
    comp_gemm_k<<<dim3(304, 5), dim3(256), 0, stream>>>(tok, redW, redb, idxb, tl_lab, tl_start, tl_cnt, ntiles, comph);
    // token scan (cooperative)
    {
        const float* a0 = tWhh; const h16* a1 = Xh; float* a2 = hbuf; float* a3 = cst; h16* a4 = tokrec;
        void* args[] = {&a0, &a1, &a2, &a3, &a4};
        hipLaunchCooperativeKernel((const void*)tok_scan_k, dim3(256), dim3(512), args, 0, stream);
    }
    // st_in = tokrec + composed @ comp_W.T + comp_b -> stinh
    gemm_k<4,false><<<dim3(256, 8), dim3(256), 0, stream>>>(compW, compb, comph, tokrec, nullptr, stinh, nWD, nH);
    // stX = st_in @ st_Wih.T + st_b -> Xh (tokX dead)
    gemm_k<1,false><<<dim3(256, 32), dim3(256), 0, stream>>>(sWih, sb, stinh, nullptr, nullptr, Xh, nH, nG);
    // action scan (cooperative): stack chain + action chain concurrently
    {
        const float* a0 = sWhh; const float* a1 = aWhh; const h16* a2 = Xh; const float* a3 = acTab;
        const int* a4 = actb; float* a5 = spbuf; float* a6 = apbuf;
        float* a7 = cs_st; float* a8 = cs_ac; h16* a9 = hsrec; h16* a10 = harec;
        void* args[] = {&a0, &a1, &a2, &a3, &a4, &a5, &a6, &a7, &a8, &a9, &a10};
        hipLaunchCooperativeKernel((const void*)act_scan_k, dim3(512), dim3(256), args, 0, stream);
    }
    // hidden = relu(feat @ h2f_W.T + h2f_b) -> Xh (stX dead)
    gemm_k<3,true><<<dim3(256, 8), dim3(256), 0, stream>>>(h2fW, h2fb, hsrec, tokrec, harec, Xh, nFH, nH);
    loss_k<<<dim3(nS * nB), dim3(128), 0, stream>>>(Xh, f2aW, f2ab, actb, losses);
    reduce_k<<<dim3(1), dim3(256), 0, stream>>>(losses, (float*)d_out);
}

// Round 3
// 14557.744 us; speedup vs baseline: 1.9884x; 1.9884x over previous
//
#include <hip/hip_runtime.h>
#include <math.h>

constexpr int nB = 64, nS = 256, nAc = 256, nH = 512, nG = 2048;
constexpr int nWD = 320, nNA = 75, nLB = 48, nFH = 2560;
constexpr int BH = nB * nH; // 32768

typedef _Float16 h16;
typedef _Float16 h16x8 __attribute__((ext_vector_type(8)));
typedef _Float16 h16x4 __attribute__((ext_vector_type(4)));

__device__ __forceinline__ float sigf(float x) { return 1.0f / (1.0f + __expf(-x)); }

// ---- lightweight 32-block group barrier (replaces grid.sync; ~µs not ~69µs) ----
// Each block release-stores its step count into its own slot; one wave
// acquire-polls all 32 slots. __syncthreads before the store drains all the
// block's prior global stores (compiler emits vmcnt(0) before s_barrier), so
// the released flag publishes the h-state written this step.
__device__ __forceinline__ void group_barrier(int* __restrict__ slots, int myslot, int target, int tid)
{
    __syncthreads();
    if (tid == 0)
        __hip_atomic_store(&slots[myslot], target, __ATOMIC_RELEASE, __HIP_MEMORY_SCOPE_AGENT);
    if (tid < 64) {
        while (__hip_atomic_load(&slots[tid & 31], __ATOMIC_ACQUIRE, __HIP_MEMORY_SCOPE_AGENT) < target)
            __builtin_amdgcn_s_sleep(1);
    }
    __syncthreads();
}

// ---------------- init: zero hsrec prefix + counters + barrier slots ----------------
__global__ void init_k(h16* __restrict__ hsrec, int* __restrict__ counts, int* __restrict__ fill,
                       int* __restrict__ bar_tok, int* __restrict__ bar_act)
{
    int i = blockIdx.x * 256 + threadIdx.x;
    if (i < 2 * BH) hsrec[i] = (h16)0.0f;
    if (i < nLB) { counts[i] = 0; fill[i] = 0; }
    if (i < 8 * 64) bar_tok[i] = 0;
    if (i < 16 * 64) bar_act[i] = 0;
}

// ---------------- embedding gather -> tok fp16 [b][s][0:320] ----------------
__global__ __launch_bounds__(64)
void embed_k(const int* __restrict__ tokb, const int* __restrict__ posb,
             const float* __restrict__ wemb, const float* __restrict__ pemb,
             h16* __restrict__ tok)
{
    const int r = blockIdx.x;            // b*nS + s
    const int tid = threadIdx.x;
    const int tk = tokb[r], pp = posb[r];
    h16x8* d = (h16x8*)(tok + (size_t)r * nWD);
    if (tid < 32) {
        const float4* sw = (const float4*)(wemb + (size_t)tk * 256);
        const float4 a = sw[2 * tid], b = sw[2 * tid + 1];
        h16x8 o;
        o[0]=(h16)a.x; o[1]=(h16)a.y; o[2]=(h16)a.z; o[3]=(h16)a.w;
        o[4]=(h16)b.x; o[5]=(h16)b.y; o[6]=(h16)b.z; o[7]=(h16)b.w;
        d[tid] = o;
    } else if (tid < 40) {
        const int q = tid - 32;
        const float4* sp = (const float4*)(pemb + (size_t)pp * 64);
        const float4 a = sp[2 * q], b = sp[2 * q + 1];
        h16x8 o;
        o[0]=(h16)a.x; o[1]=(h16)a.y; o[2]=(h16)a.z; o[3]=(h16)a.w;
        o[4]=(h16)b.x; o[5]=(h16)b.y; o[6]=(h16)b.z; o[7]=(h16)b.w;
        d[32 + q] = o;
    }
}

// ---------------- action-gate table: acTab[a][j] = aemb[a]·aWih[j] + ab[j] ----------------
__global__ __launch_bounds__(256)
void actab_k(const float* __restrict__ aemb, const float* __restrict__ aWih,
             const float* __restrict__ ab, float* __restrict__ acTab)
{
    const int a = blockIdx.x;            // 0..74
    __shared__ float ae[64];
    const int tid = threadIdx.x;
    if (tid < 64) ae[tid] = aemb[a * 64 + tid];
    __syncthreads();
    for (int j = tid; j < nG; j += 256) {
        const float* wr = aWih + (size_t)j * 64;
        float s = ab[j];
        #pragma unroll
        for (int k = 0; k < 64; k += 4) {
            const float4 w = *(const float4*)(wr + k);
            s = fmaf(w.x, ae[k], s);     s = fmaf(w.y, ae[k + 1], s);
            s = fmaf(w.z, ae[k + 2], s); s = fmaf(w.w, ae[k + 3], s);
        }
        acTab[(size_t)a * nG + j] = s;
    }
}

// ---------------- fp16-in / fp16-out GEMM: C[r][n] = Arow(r)·Wm[n][:] + bias[n] ----------------
template<int MODE, bool RELU>
__global__ __launch_bounds__(256)
void gemm_k(const float* __restrict__ Wm, const float* __restrict__ bias,
            const h16* __restrict__ A0, const h16* __restrict__ A1,
            const h16* __restrict__ A2, h16* __restrict__ C, int Ktot, int ldC)
{
    const int bm = blockIdx.x << 6, bn = blockIdx.y << 6;
    const int tid = threadIdx.x;
    const int alm = tid >> 1, alk = (tid & 1) << 3;     // A: 128 threads x 8 halfs
    const int wlm = tid >> 2, wlk = (tid & 3) << 2;     // W: 256 threads x float4
    const int trow = tid >> 4, tcol = tid & 15;
    __shared__ __align__(16) float As[16][68];
    __shared__ __align__(16) float Ws[16][68];
    const int r = bm + alm;
    const h16* arow = nullptr;
    if (MODE == 0) { const int b = r & 63, s = r >> 6; arow = A0 + ((size_t)b * nS + s) * nWD; }
    if (MODE == 1) { arow = A0 + (size_t)r * nH; }
    if (MODE == 4) { arow = A0 + (size_t)r * nWD; }
    const float* wrow = Wm + (size_t)(bn + wlm) * Ktot;
    float acc[4][4] = {};
    for (int k0 = 0; k0 < Ktot; k0 += 16) {
        h16x8 av;
        if (tid < 128) {
            if (MODE == 3) {
                const int p = k0 >> 9;
                const h16* base = (p == 0) ? A0 + 2 * BH : (p == 1) ? A0 + BH
                                : (p == 2) ? A0 : (p == 3) ? A1 : A2;
                av = *(const h16x8*)(base + (size_t)r * nH + (k0 & 511) + alk);
            } else {
                av = *(const h16x8*)(arow + k0 + alk);
            }
        }
        const float4 wv = *(const float4*)(wrow + k0 + wlk);
        __syncthreads();
        if (tid < 128) {
            #pragma unroll
            for (int j = 0; j < 8; ++j) As[alk + j][alm] = (float)av[j];
        }
        Ws[wlk + 0][wlm] = wv.x; Ws[wlk + 1][wlm] = wv.y;
        Ws[wlk + 2][wlm] = wv.z; Ws[wlk + 3][wlm] = wv.w;
        __syncthreads();
        #pragma unroll
        for (int kk = 0; kk < 16; ++kk) {
            const float4 a4 = *(const float4*)&As[kk][trow << 2];
            const float4 w4 = *(const float4*)&Ws[kk][tcol << 2];
            const float aa[4] = {a4.x, a4.y, a4.z, a4.w};
            const float ww[4] = {w4.x, w4.y, w4.z, w4.w};
            #pragma unroll
            for (int i = 0; i < 4; ++i)
                #pragma unroll
                for (int j = 0; j < 4; ++j)
                    acc[i][j] = fmaf(aa[i], ww[j], acc[i][j]);
        }
    }
    #pragma unroll
    for (int i = 0; i < 4; ++i) {
        const int rr = bm + (trow << 2) + i;
        const int cc = bn + (tcol << 2);
        h16x4 v;
        #pragma unroll
        for (int j = 0; j < 4; ++j) {
            float x = acc[i][j] + bias[cc + j];
            if (MODE == 4) x += (float)A1[(size_t)rr * nH + cc + j];
            if (RELU) x = fmaxf(x, 0.0f);
            v[j] = (h16)x;
        }
        *(h16x4*)(C + (size_t)rr * ldC + cc) = v;
    }
}

// ---------------- label sort for red_W batched GEMM ----------------
__global__ void hist_k(const int* __restrict__ actb, int* __restrict__ lab, int* __restrict__ counts)
{
    const int r = blockIdx.x * 256 + threadIdx.x;   // r = t*64+b
    const int t = r >> 6, b = r & 63;
    const int a = actb[b * nAc + t];
    const int l = a % nLB;
    lab[r] = l;
    atomicAdd(&counts[l], 1);
}

__global__ void tiles_k(const int* __restrict__ counts, int* __restrict__ offs,
                        int* __restrict__ tl_lab, int* __restrict__ tl_start,
                        int* __restrict__ tl_cnt, int* __restrict__ ntiles)
{
    if (blockIdx.x == 0 && threadIdx.x == 0) {
        int o = 0, nt = 0;
        for (int l = 0; l < nLB; ++l) {
            offs[l] = o;
            const int c = counts[l];
            for (int s0 = 0; s0 < c; s0 += 64) {
                tl_lab[nt] = l; tl_start[nt] = o + s0; tl_cnt[nt] = min(64, c - s0); ++nt;
            }
            o += c;
        }
        offs[nLB] = o;
        ntiles[0] = nt;
    }
}

__global__ void scatter_k(const int* __restrict__ lab, const int* __restrict__ offs,
                          int* __restrict__ fill, int* __restrict__ idx)
{
    const int r = blockIdx.x * 256 + threadIdx.x;
    const int l = lab[r];
    const int pos = offs[l] + atomicAdd(&fill[l], 1);
    idx[pos] = r;
}

// composed[r][i] = tanh( pair(r)·red_W[l][i][:] + red_b[l][i] ), rows grouped by label
__global__ __launch_bounds__(256)
void comp_gemm_k(const h16* __restrict__ tok, const float* __restrict__ redW,
                 const float* __restrict__ redb, const int* __restrict__ idx,
                 const int* __restrict__ tl_lab, const int* __restrict__ tl_start,
                 const int* __restrict__ tl_cnt, const int* __restrict__ ntiles,
                 h16* __restrict__ comp)
{
    const int tile = blockIdx.x;
    if (tile >= ntiles[0]) return;
    const int cn0 = blockIdx.y << 6;
    const int l = tl_lab[tile], rst = tl_start[tile], mrows = tl_cnt[tile];
    __shared__ int rows_s[64];
    __shared__ __align__(16) float As[16][68];
    __shared__ __align__(16) float Ws[16][68];
    const int tid = threadIdx.x;
    if (tid < 64) rows_s[tid] = (tid < mrows) ? idx[rst + tid] : -1;
    __syncthreads();
    const int alm = tid >> 1, alk = (tid & 1) << 3;
    const int wlm = tid >> 2, wlk = (tid & 3) << 2;
    const int trow = tid >> 4, tcol = tid & 15;
    const int rm = (tid < 128) ? rows_s[alm] : -1;
    const h16* arow0 = tok;
    const h16* arow1 = tok;
    if (rm >= 0) {
        const int b = rm & 63, t = rm >> 6;
        arow0 = tok + ((size_t)b * nS + t) * nWD;
        arow1 = tok + ((size_t)b * nS + max(t - 1, 0)) * nWD;
    }
    const float* wrow = redW + (size_t)l * (320 * 640) + (size_t)(cn0 + wlm) * 640;
    float acc[4][4] = {};
    for (int k0 = 0; k0 < 640; k0 += 16) {
        const int k = k0 + alk;
        h16x8 av = {};
        if (rm >= 0) av = (k < 320) ? *(const h16x8*)(arow0 + k)
                                    : *(const h16x8*)(arow1 + (k - 320));
        const float4 wv = *(const float4*)(wrow + k0 + wlk);
        __syncthreads();
        if (tid < 128) {
            #pragma unroll
            for (int j = 0; j < 8; ++j) As[alk + j][alm] = (float)av[j];
        }
        Ws[wlk + 0][wlm] = wv.x; Ws[wlk + 1][wlm] = wv.y;
        Ws[wlk + 2][wlm] = wv.z; Ws[wlk + 3][wlm] = wv.w;
        __syncthreads();
        #pragma unroll
        for (int kk = 0; kk < 16; ++kk) {
            const float4 a4 = *(const float4*)&As[kk][trow << 2];
            const float4 w4 = *(const float4*)&Ws[kk][tcol << 2];
            const float aa[4] = {a4.x, a4.y, a4.z, a4.w};
            const float ww[4] = {w4.x, w4.y, w4.z, w4.w};
            #pragma unroll
            for (int i = 0; i < 4; ++i)
                #pragma unroll
                for (int j = 0; j < 4; ++j)
                    acc[i][j] = fmaf(aa[i], ww[j], acc[i][j]);
        }
    }
    #pragma unroll
    for (int i = 0; i < 4; ++i) {
        const int rr = rows_s[(trow << 2) + i];
        if (rr < 0) continue;
        #pragma unroll
        for (int j = 0; j < 4; ++j) {
            const int cc = cn0 + (tcol << 2) + j;
            comp[(size_t)rr * nWD + cc] = (h16)tanhf(acc[i][j] + redb[l * nWD + cc]);
        }
    }
}

// ---------------- token LSTM scan (cooperative launch for co-residency) ----------------
// 256 blocks x 512 thr; group = 32 blocks sharing batch-group g; per-group flag barrier.
__global__ __launch_bounds__(512)
void tok_scan_k(const float* __restrict__ Whh, const h16* __restrict__ gx,
                float* __restrict__ hbuf, h16* __restrict__ tokrec,
                int* __restrict__ bar)
{
    const int blk = blockIdx.x;
    const int g = blk >> 5, jb = blk & 31;
    const int tid = threadIdx.x;
    const int kg = tid & 7, r64 = tid >> 3;
    const int c = r64 >> 4, jl = r64 & 15;
    const int grow = c * nH + (jb << 4) + jl;
    const float* wrow = Whh + (size_t)grow * nH;
    const int r64u = tid & 63, bu = tid >> 6;
    const int grow_u = (r64u >> 4) * nH + (jb << 4) + (r64u & 15);
    int* slots = bar + g * 64;
    __shared__ __align__(16) float hsm[8][nH];
    __shared__ float ps[8][8][65];
    __shared__ float gex[64][9];
    float c_reg = 0.0f;   // cell state, private to writer threads (tid<128)
    for (int t = 0; t < nS; ++t) {
        if (t == 0) {
            for (int i = tid; i < 8 * nH; i += 512) ((float*)hsm)[i] = 0.0f;
        } else {
            const float4* src = (const float4*)(hbuf + (size_t)((t - 1) & 1) * BH + (g << 3) * nH);
            float4* dst = (float4*)hsm;
            #pragma unroll
            for (int i2 = 0; i2 < 2; ++i2) dst[tid + i2 * 512] = src[tid + i2 * 512];
        }
        __syncthreads();
        const float gxv = (float)gx[(size_t)((t << 6) + (g << 3) + bu) * nG + grow_u];
        float acc[8] = {0.f,0.f,0.f,0.f,0.f,0.f,0.f,0.f};
        #pragma unroll 4
        for (int i = 0; i < 16; ++i) {
            const int k = (i << 5) + (kg << 2);
            const float4 wv = *(const float4*)(wrow + k);
            #pragma unroll
            for (int b = 0; b < 8; ++b) {
                const float4 hv = *(const float4*)(&hsm[b][k]);
                acc[b] = fmaf(wv.x, hv.x, acc[b]);
                acc[b] = fmaf(wv.y, hv.y, acc[b]);
                acc[b] = fmaf(wv.z, hv.z, acc[b]);
                acc[b] = fmaf(wv.w, hv.w, acc[b]);
            }
        }
        #pragma unroll
        for (int b = 0; b < 8; ++b) ps[kg][b][r64] = acc[b];
        __syncthreads();
        float gsum = gxv;
        #pragma unroll
        for (int k2 = 0; k2 < 8; ++k2) gsum += ps[k2][bu][r64u];
        gex[r64u][bu] = gsum;
        __syncthreads();
        if (tid < 128) {
            const int jl2 = tid >> 3, b2 = tid & 7;
            const float gi = gex[jl2][b2];
            const float gf = gex[16 + jl2][b2];
            const float gg = gex[32 + jl2][b2];
            const float go = gex[48 + jl2][b2];
            const int bg = (g << 3) + b2, jh = (jb << 4) + jl2;
            const float cn = sigf(gf) * c_reg + sigf(gi) * tanhf(gg);
            const float hn = sigf(go) * tanhf(cn);
            c_reg = cn;
            hbuf[(size_t)(t & 1) * BH + bg * nH + jh] = hn;
            tokrec[(size_t)t * BH + bg * nH + jh] = (h16)hn;
        }
        if (t + 1 < nS) group_barrier(slots, jb, t + 1, tid);
    }
}

// ---------------- action scan: two independent LSTM chains ----------------
// 512 blocks x 256 thr; group = (role, g) -> 32 blocks; per-group flag barrier.
__global__ __launch_bounds__(256)
void act_scan_k(const float* __restrict__ sWhh, const float* __restrict__ aWhh,
                const h16* __restrict__ stX, const float* __restrict__ acTab,
                const int* __restrict__ actb,
                float* __restrict__ spbuf, float* __restrict__ apbuf,
                h16* __restrict__ hsrec, h16* __restrict__ harec,
                int* __restrict__ bar)
{
    const int blk = blockIdx.x;
    const int role = blk >> 8;              // 0 = stack LSTM, 1 = action LSTM
    const int sub = blk & 255;
    const int g = sub >> 5, jb = sub & 31;
    const int tid = threadIdx.x;
    const int kg = tid & 3, r64 = tid >> 2;
    const int c = r64 >> 4, jl = r64 & 15;
    const int grow = c * nH + (jb << 4) + jl;
    const float* Whh = role ? aWhh : sWhh;
    float* pbuf      = role ? apbuf : spbuf;
    const float* wrow = Whh + (size_t)grow * nH;
    const int r64u = tid & 63, bu0 = (tid >> 6) << 1;
    const int grow_u = (r64u >> 4) * nH + (jb << 4) + (r64u & 15);
    int* slots = bar + (role * 8 + g) * 64;
    __shared__ __align__(16) float hsm[8][nH];
    __shared__ float ps[4][8][65];
    __shared__ float gex[64][9];
    __shared__ int aidx[8];
    float c_reg = 0.0f;   // cell state, private to writer threads (tid<128)
    for (int t = 0; t < nAc; ++t) {
        if (t == 0) {
            for (int i = tid; i < 8 * nH; i += 256) ((float*)hsm)[i] = 0.0f;
        } else {
            const float4* src = (const float4*)(pbuf + (size_t)((t - 1) & 1) * BH + (g << 3) * nH);
            float4* dst = (float4*)hsm;
            #pragma unroll
            for (int i2 = 0; i2 < 4; ++i2) dst[tid + i2 * 256] = src[tid + i2 * 256];
        }
        if (role && tid < 8) aidx[tid] = actb[((g << 3) + tid) * nAc + t];
        __syncthreads();
        float gpre[2];
        #pragma unroll
        for (int bb = 0; bb < 2; ++bb) {
            if (role) gpre[bb] = acTab[(size_t)aidx[bu0 + bb] * nG + grow_u];
            else      gpre[bb] = (float)stX[(size_t)((t << 6) + (g << 3) + bu0 + bb) * nG + grow_u];
        }
        float acc[8] = {0.f,0.f,0.f,0.f,0.f,0.f,0.f,0.f};
        #pragma unroll 4
        for (int i = 0; i < 32; ++i) {
            const int k = (i << 4) + (kg << 2);
            const float4 wv = *(const float4*)(wrow + k);
            #pragma unroll
            for (int b = 0; b < 8; ++b) {
                const float4 hv = *(const float4*)(&hsm[b][k]);
                acc[b] = fmaf(wv.x, hv.x, acc[b]);
                acc[b] = fmaf(wv.y, hv.y, acc[b]);
                acc[b] = fmaf(wv.z, hv.z, acc[b]);
                acc[b] = fmaf(wv.w, hv.w, acc[b]);
            }
        }
        #pragma unroll
        for (int b = 0; b < 8; ++b) ps[kg][b][r64] = acc[b];
        __syncthreads();
        #pragma unroll
        for (int bb = 0; bb < 2; ++bb) {
            float gsum = gpre[bb];
            #pragma unroll
            for (int k2 = 0; k2 < 4; ++k2) gsum += ps[k2][bu0 + bb][r64u];
            gex[r64u][bu0 + bb] = gsum;
        }
        __syncthreads();
        if (tid < 128) {
            const int jl2 = tid >> 3, b2 = tid & 7;
            const float gi = gex[jl2][b2];
            const float gf = gex[16 + jl2][b2];
            const float gg = gex[32 + jl2][b2];
            const float go = gex[48 + jl2][b2];
            const int bg = (g << 3) + b2, jh = (jb << 4) + jl2;
            const float cn = sigf(gf) * c_reg + sigf(gi) * tanhf(gg);
            const float hn = sigf(go) * tanhf(cn);
            c_reg = cn;
            pbuf[(size_t)(t & 1) * BH + bg * nH + jh] = hn;
            if (role) harec[(size_t)t * BH + bg * nH + jh] = (h16)hn;
            else      hsrec[(size_t)(t + 2) * BH + bg * nH + jh] = (h16)hn;
        }
        if (t + 1 < nAc) group_barrier(slots, jb, t + 1, tid);
    }
}

// ---------------- per-(t,b) logits + log-softmax loss ----------------
__global__ __launch_bounds__(128)
void loss_k(const h16* __restrict__ hidden, const float* __restrict__ f2aW,
            const float* __restrict__ f2ab, const int* __restrict__ actb,
            float* __restrict__ losses)
{
    const int r = blockIdx.x;
    const int t = r >> 6, b = r & 63;
    __shared__ __align__(16) float hrow[nH];
    __shared__ float lg[nNA + 1];
    const int tid = threadIdx.x;
    if (tid < 64) {
        const h16x8 v = ((const h16x8*)(hidden + (size_t)r * nH))[tid];
        #pragma unroll
        for (int j = 0; j < 8; ++j) hrow[tid * 8 + j] = (float)v[j];
    }
    __syncthreads();
    if (tid < nNA) {
        const float* wr = f2aW + (size_t)tid * nH;
        float a = f2ab[tid];
        for (int k = 0; k < nH; k += 4) {
            const float4 wv = *(const float4*)(wr + k);
            const float4 hv = *(const float4*)(&hrow[k]);
            a = fmaf(wv.x, hv.x, a); a = fmaf(wv.y, hv.y, a);
            a = fmaf(wv.z, hv.z, a); a = fmaf(wv.w, hv.w, a);
        }
        lg[tid] = a;
    }
    __syncthreads();
    if (tid < 64) {
        float m = -1e30f;
        for (int i = tid; i < nNA; i += 64) m = fmaxf(m, lg[i]);
        #pragma unroll
        for (int o = 32; o > 0; o >>= 1) m = fmaxf(m, __shfl_xor(m, o));
        float s = 0.0f;
        for (int i = tid; i < nNA; i += 64) s += __expf(lg[i] - m);
        #pragma unroll
        for (int o = 32; o > 0; o >>= 1) s += __shfl_xor(s, o);
        if (tid == 0) {
            const int a = actb[b * nAc + t];
            losses[r] = m + logf(s) - lg[a];
        }
    }
}

__global__ __launch_bounds__(256)
void reduce_k(const float* __restrict__ losses, float* __restrict__ out)
{
    __shared__ float sm[256];
    const int tid = threadIdx.x;
    float a = 0.0f;
    for (int i = tid; i < nS * nB; i += 256) a += losses[i];
    sm[tid] = a; __syncthreads();
    for (int s = 128; s > 0; s >>= 1) { if (tid < s) sm[tid] += sm[tid + s]; __syncthreads(); }
    if (tid == 0) out[0] = sm[0] * (1.0f / 16384.0f);
}

// ---------------- launch ----------------
extern "C" void kernel_launch(void* const* d_in, const int* in_sizes, int n_in,
                              void* d_out, int out_size, void* d_ws, size_t ws_size,
                              hipStream_t stream)
{
    const int*   tokb  = (const int*)  d_in[0];
    const int*   posb  = (const int*)  d_in[1];
    const int*   actb  = (const int*)  d_in[3];
    const float* wemb  = (const float*)d_in[4];
    const float* pemb  = (const float*)d_in[5];
    const float* aemb  = (const float*)d_in[6];
    const float* tWih  = (const float*)d_in[7];
    const float* tWhh  = (const float*)d_in[8];
    const float* tb    = (const float*)d_in[9];
    const float* sWih  = (const float*)d_in[10];
    const float* sWhh  = (const float*)d_in[11];
    const float* sb    = (const float*)d_in[12];
    const float* aWih  = (const float*)d_in[13];
    const float* aWhh  = (const float*)d_in[14];
    const float* ab    = (const float*)d_in[15];
    const float* redW  = (const float*)d_in[16];
    const float* redb  = (const float*)d_in[17];
    const float* compW = (const float*)d_in[18];
    const float* compb = (const float*)d_in[19];
    const float* h2fW  = (const float*)d_in[20];
    const float* h2fb  = (const float*)d_in[21];
    const float* f2aW  = (const float*)d_in[22];
    const float* f2ab  = (const float*)d_in[23];

    // ---- workspace carve (~123 MB total) ----
    char* base = (char*)d_ws;
    auto carve = [&](size_t bytes) { char* p = base; base += (bytes + 255) & ~(size_t)255; return p; };
    h16*   tok    = (h16*)  carve((size_t)nB * nS * nWD * 2);        // 10.5 MB
    h16*   Xh     = (h16*)  carve((size_t)nS * nB * nG * 2);         // 32 MB (tokX -> stX -> hidden)
    h16*   comph  = (h16*)  carve((size_t)nS * nB * nWD * 2);        // 10.5 MB
    h16*   stinh  = (h16*)  carve((size_t)nS * BH * 2);              // 16 MB
    h16*   tokrec = (h16*)  carve((size_t)nS * BH * 2);              // 16 MB
    h16*   hsrec  = (h16*)  carve((size_t)(nS + 2) * BH * 2);        // 16.9 MB
    h16*   harec  = (h16*)  carve((size_t)nS * BH * 2);              // 16 MB
    float* acTab  = (float*)carve((size_t)nNA * nG * 4);             // 0.6 MB
    float* hbuf   = (float*)carve((size_t)2 * BH * 4);
    float* spbuf  = (float*)carve((size_t)2 * BH * 4);
    float* apbuf  = (float*)carve((size_t)2 * BH * 4);
    float* losses = (float*)carve((size_t)nS * nB * 4);
    int*   bar_tok  = (int*)carve(8 * 64 * 4);
    int*   bar_act  = (int*)carve(16 * 64 * 4);
    int*   lab      = (int*)carve((size_t)nS * nB * 4);
    int*   counts   = (int*)carve(nLB * 4);
    int*   offs     = (int*)carve((nLB + 1) * 4);
    int*   fill     = (int*)carve(nLB * 4);
    int*   tl_lab   = (int*)carve(320 * 4);
    int*   tl_start = (int*)carve(320 * 4);
    int*   tl_cnt   = (int*)carve(320 * 4);
    int*   ntiles   = (int*)carve(4);
    int*   idxb     = (int*)carve((size_t)nS * nB * 4);

    init_k<<<dim3(256), dim3(256), 0, stream>>>(hsrec, counts, fill, bar_tok, bar_act);
    embed_k<<<dim3(nB * nS), dim3(64), 0, stream>>>(tokb, posb, wemb, pemb, tok);
    actab_k<<<dim3(nNA), dim3(256), 0, stream>>>(aemb, aWih, ab, acTab);
    // tokX = tok @ tok_Wih.T + tok_b  -> Xh
    gemm_k<0,false><<<dim3(256, 32), dim3(256), 0, stream>>>(tWih, tb, tok, nullptr, nullptr, Xh, nWD, nG);
    // label sort + composed
    hist_k<<<dim3(64), dim3(256), 0, stream>>>(actb, lab, counts);
    tiles_k<<<dim3(1), dim3(64), 0, stream>>>(counts, offs, tl_lab, tl_start, tl_cnt, ntiles);
    scatter_k<<<dim3(64), dim3(256), 0, stream>>>(lab, offs, fill, idxb);
    comp_gemm_k<<<dim3(304, 5), dim3(256), 0, stream>>>(tok, redW, redb, idxb, tl_lab, tl_start, tl_cnt, ntiles, comph);
    // token scan (cooperative launch for co-residency; custom group barriers inside)
    {
        const float* a0 = tWhh; const h16* a1 = Xh; float* a2 = hbuf; h16* a3 = tokrec; int* a4 = bar_tok;
        void* args[] = {&a0, &a1, &a2, &a3, &a4};
        hipLaunchCooperativeKernel((const void*)tok_scan_k, dim3(256), dim3(512), args, 0, stream);
    }
    // st_in = tokrec + composed @ comp_W.T + comp_b -> stinh
    gemm_k<4,false><<<dim3(256, 8), dim3(256), 0, stream>>>(compW, compb, comph, tokrec, nullptr, stinh, nWD, nH);
    // stX = st_in @ st_Wih.T + st_b -> Xh (tokX dead)
    gemm_k<1,false><<<dim3(256, 32), dim3(256), 0, stream>>>(sWih, sb, stinh, nullptr, nullptr, Xh, nH, nG);
    // action scan (cooperative): stack chain + action chain concurrently
    {
        const float* a0 = sWhh; const float* a1 = aWhh; const h16* a2 = Xh; const float* a3 = acTab;
        const int* a4 = actb; float* a5 = spbuf; float* a6 = apbuf;
        h16* a7 = hsrec; h16* a8 = harec; int* a9 = bar_act;
        void* args[] = {&a0, &a1, &a2, &a3, &a4, &a5, &a6, &a7, &a8, &a9};
        hipLaunchCooperativeKernel((const void*)act_scan_k, dim3(512), dim3(256), args, 0, stream);
    }
    // hidden = relu(feat @ h2f_W.T + h2f_b) -> Xh (stX dead)
    gemm_k<3,true><<<dim3(256, 8), dim3(256), 0, stream>>>(h2fW, h2fb, hsrec, tokrec, harec, Xh, nFH, nH);
    loss_k<<<dim3(nS * nB), dim3(128), 0, stream>>>(Xh, f2aW, f2ab, actb, losses);
    reduce_k<<<dim3(1), dim3(256), 0, stream>>>(losses, (float*)d_out);
}

// Round 4
// 5853.050 us; speedup vs baseline: 4.9457x; 2.4872x over previous
//
#include <hip/hip_runtime.h>
#include <math.h>

constexpr int nB = 64, nS = 256, nAc = 256, nH = 512, nG = 2048;
constexpr int nWD = 320, nNA = 75, nLB = 48, nFH = 2560;
constexpr int BH = nB * nH; // 32768

typedef _Float16 h16;
typedef _Float16 h16x8 __attribute__((ext_vector_type(8)));
typedef _Float16 h16x4 __attribute__((ext_vector_type(4)));
typedef _Float16 h16x2 __attribute__((ext_vector_type(2)));
typedef unsigned long long u64t;

__device__ __forceinline__ float sigf(float x) { return 1.0f / (1.0f + __expf(-x)); }

// ---------------- init: zero hsrec prefix + counters + barrier slots ----------------
__global__ void init_k(h16* __restrict__ hsrec, int* __restrict__ counts, int* __restrict__ fill,
                       int* __restrict__ bar_tok, int* __restrict__ bar_act)
{
    int i = blockIdx.x * 256 + threadIdx.x;
    if (i < 2 * BH) hsrec[i] = (h16)0.0f;
    if (i < nLB) { counts[i] = 0; fill[i] = 0; }
    if (i < 8 * 64) bar_tok[i] = 0;
    if (i < 16 * 64) bar_act[i] = 0;
}

// ---------------- weight fp32 -> fp16 conversion (Whh x3) ----------------
__global__ __launch_bounds__(256)
void wcvt_k(const float* __restrict__ w0, const float* __restrict__ w1, const float* __restrict__ w2,
            h16* __restrict__ o0, h16* __restrict__ o1, h16* __restrict__ o2)
{
    const int i = blockIdx.x * 256 + threadIdx.x;   // float4 index; 2048*512/4 = 262144 per matrix
    {
        const float4 a = ((const float4*)w0)[i];
        h16x4 v; v[0]=(h16)a.x; v[1]=(h16)a.y; v[2]=(h16)a.z; v[3]=(h16)a.w;
        ((h16x4*)o0)[i] = v;
    }
    {
        const float4 a = ((const float4*)w1)[i];
        h16x4 v; v[0]=(h16)a.x; v[1]=(h16)a.y; v[2]=(h16)a.z; v[3]=(h16)a.w;
        ((h16x4*)o1)[i] = v;
    }
    {
        const float4 a = ((const float4*)w2)[i];
        h16x4 v; v[0]=(h16)a.x; v[1]=(h16)a.y; v[2]=(h16)a.z; v[3]=(h16)a.w;
        ((h16x4*)o2)[i] = v;
    }
}

// ---------------- embedding gather -> tok fp16 [b][s][0:320] ----------------
__global__ __launch_bounds__(64)
void embed_k(const int* __restrict__ tokb, const int* __restrict__ posb,
             const float* __restrict__ wemb, const float* __restrict__ pemb,
             h16* __restrict__ tok)
{
    const int r = blockIdx.x;            // b*nS + s
    const int tid = threadIdx.x;
    const int tk = tokb[r], pp = posb[r];
    h16x8* d = (h16x8*)(tok + (size_t)r * nWD);
    if (tid < 32) {
        const float4* sw = (const float4*)(wemb + (size_t)tk * 256);
        const float4 a = sw[2 * tid], b = sw[2 * tid + 1];
        h16x8 o;
        o[0]=(h16)a.x; o[1]=(h16)a.y; o[2]=(h16)a.z; o[3]=(h16)a.w;
        o[4]=(h16)b.x; o[5]=(h16)b.y; o[6]=(h16)b.z; o[7]=(h16)b.w;
        d[tid] = o;
    } else if (tid < 40) {
        const int q = tid - 32;
        const float4* sp = (const float4*)(pemb + (size_t)pp * 64);
        const float4 a = sp[2 * q], b = sp[2 * q + 1];
        h16x8 o;
        o[0]=(h16)a.x; o[1]=(h16)a.y; o[2]=(h16)a.z; o[3]=(h16)a.w;
        o[4]=(h16)b.x; o[5]=(h16)b.y; o[6]=(h16)b.z; o[7]=(h16)b.w;
        d[32 + q] = o;
    }
}

// ---------------- action-gate table: acTab[a][j] = aemb[a]·aWih[j] + ab[j] ----------------
__global__ __launch_bounds__(256)
void actab_k(const float* __restrict__ aemb, const float* __restrict__ aWih,
             const float* __restrict__ ab, float* __restrict__ acTab)
{
    const int a = blockIdx.x;            // 0..74
    __shared__ float ae[64];
    const int tid = threadIdx.x;
    if (tid < 64) ae[tid] = aemb[a * 64 + tid];
    __syncthreads();
    for (int j = tid; j < nG; j += 256) {
        const float* wr = aWih + (size_t)j * 64;
        float s = ab[j];
        #pragma unroll
        for (int k = 0; k < 64; k += 4) {
            const float4 w = *(const float4*)(wr + k);
            s = fmaf(w.x, ae[k], s);     s = fmaf(w.y, ae[k + 1], s);
            s = fmaf(w.z, ae[k + 2], s); s = fmaf(w.w, ae[k + 3], s);
        }
        acTab[(size_t)a * nG + j] = s;
    }
}

// ---------------- fp16-in / fp16-out GEMM: C[r][n] = Arow(r)·Wm[n][:] + bias[n] ----------------
template<int MODE, bool RELU>
__global__ __launch_bounds__(256)
void gemm_k(const float* __restrict__ Wm, const float* __restrict__ bias,
            const h16* __restrict__ A0, const h16* __restrict__ A1,
            const h16* __restrict__ A2, h16* __restrict__ C, int Ktot, int ldC)
{
    const int bm = blockIdx.x << 6, bn = blockIdx.y << 6;
    const int tid = threadIdx.x;
    const int alm = tid >> 1, alk = (tid & 1) << 3;     // A: 128 threads x 8 halfs
    const int wlm = tid >> 2, wlk = (tid & 3) << 2;     // W: 256 threads x float4
    const int trow = tid >> 4, tcol = tid & 15;
    __shared__ __align__(16) float As[16][68];
    __shared__ __align__(16) float Ws[16][68];
    const int r = bm + alm;
    const h16* arow = nullptr;
    if (MODE == 0) { const int b = r & 63, s = r >> 6; arow = A0 + ((size_t)b * nS + s) * nWD; }
    if (MODE == 1) { arow = A0 + (size_t)r * nH; }
    if (MODE == 4) { arow = A0 + (size_t)r * nWD; }
    const float* wrow = Wm + (size_t)(bn + wlm) * Ktot;
    float acc[4][4] = {};
    for (int k0 = 0; k0 < Ktot; k0 += 16) {
        h16x8 av;
        if (tid < 128) {
            if (MODE == 3) {
                const int p = k0 >> 9;
                const h16* base = (p == 0) ? A0 + 2 * BH : (p == 1) ? A0 + BH
                                : (p == 2) ? A0 : (p == 3) ? A1 : A2;
                av = *(const h16x8*)(base + (size_t)r * nH + (k0 & 511) + alk);
            } else {
                av = *(const h16x8*)(arow + k0 + alk);
            }
        }
        const float4 wv = *(const float4*)(wrow + k0 + wlk);
        __syncthreads();
        if (tid < 128) {
            #pragma unroll
            for (int j = 0; j < 8; ++j) As[alk + j][alm] = (float)av[j];
        }
        Ws[wlk + 0][wlm] = wv.x; Ws[wlk + 1][wlm] = wv.y;
        Ws[wlk + 2][wlm] = wv.z; Ws[wlk + 3][wlm] = wv.w;
        __syncthreads();
        #pragma unroll
        for (int kk = 0; kk < 16; ++kk) {
            const float4 a4 = *(const float4*)&As[kk][trow << 2];
            const float4 w4 = *(const float4*)&Ws[kk][tcol << 2];
            const float aa[4] = {a4.x, a4.y, a4.z, a4.w};
            const float ww[4] = {w4.x, w4.y, w4.z, w4.w};
            #pragma unroll
            for (int i = 0; i < 4; ++i)
                #pragma unroll
                for (int j = 0; j < 4; ++j)
                    acc[i][j] = fmaf(aa[i], ww[j], acc[i][j]);
        }
    }
    #pragma unroll
    for (int i = 0; i < 4; ++i) {
        const int rr = bm + (trow << 2) + i;
        const int cc = bn + (tcol << 2);
        h16x4 v;
        #pragma unroll
        for (int j = 0; j < 4; ++j) {
            float x = acc[i][j] + bias[cc + j];
            if (MODE == 4) x += (float)A1[(size_t)rr * nH + cc + j];
            if (RELU) x = fmaxf(x, 0.0f);
            v[j] = (h16)x;
        }
        *(h16x4*)(C + (size_t)rr * ldC + cc) = v;
    }
}

// ---------------- label sort for red_W batched GEMM ----------------
__global__ void hist_k(const int* __restrict__ actb, int* __restrict__ lab, int* __restrict__ counts)
{
    const int r = blockIdx.x * 256 + threadIdx.x;   // r = t*64+b
    const int t = r >> 6, b = r & 63;
    const int a = actb[b * nAc + t];
    const int l = a % nLB;
    lab[r] = l;
    atomicAdd(&counts[l], 1);
}

__global__ void tiles_k(const int* __restrict__ counts, int* __restrict__ offs,
                        int* __restrict__ tl_lab, int* __restrict__ tl_start,
                        int* __restrict__ tl_cnt, int* __restrict__ ntiles)
{
    if (blockIdx.x == 0 && threadIdx.x == 0) {
        int o = 0, nt = 0;
        for (int l = 0; l < nLB; ++l) {
            offs[l] = o;
            const int c = counts[l];
            for (int s0 = 0; s0 < c; s0 += 64) {
                tl_lab[nt] = l; tl_start[nt] = o + s0; tl_cnt[nt] = min(64, c - s0); ++nt;
            }
            o += c;
        }
        offs[nLB] = o;
        ntiles[0] = nt;
    }
}

__global__ void scatter_k(const int* __restrict__ lab, const int* __restrict__ offs,
                          int* __restrict__ fill, int* __restrict__ idx)
{
    const int r = blockIdx.x * 256 + threadIdx.x;
    const int l = lab[r];
    const int pos = offs[l] + atomicAdd(&fill[l], 1);
    idx[pos] = r;
}

// composed[r][i] = tanh( pair(r)·red_W[l][i][:] + red_b[l][i] ), rows grouped by label
__global__ __launch_bounds__(256)
void comp_gemm_k(const h16* __restrict__ tok, const float* __restrict__ redW,
                 const float* __restrict__ redb, const int* __restrict__ idx,
                 const int* __restrict__ tl_lab, const int* __restrict__ tl_start,
                 const int* __restrict__ tl_cnt, const int* __restrict__ ntiles,
                 h16* __restrict__ comp)
{
    const int tile = blockIdx.x;
    if (tile >= ntiles[0]) return;
    const int cn0 = blockIdx.y << 6;
    const int l = tl_lab[tile], rst = tl_start[tile], mrows = tl_cnt[tile];
    __shared__ int rows_s[64];
    __shared__ __align__(16) float As[16][68];
    __shared__ __align__(16) float Ws[16][68];
    const int tid = threadIdx.x;
    if (tid < 64) rows_s[tid] = (tid < mrows) ? idx[rst + tid] : -1;
    __syncthreads();
    const int alm = tid >> 1, alk = (tid & 1) << 3;
    const int wlm = tid >> 2, wlk = (tid & 3) << 2;
    const int trow = tid >> 4, tcol = tid & 15;
    const int rm = (tid < 128) ? rows_s[alm] : -1;
    const h16* arow0 = tok;
    const h16* arow1 = tok;
    if (rm >= 0) {
        const int b = rm & 63, t = rm >> 6;
        arow0 = tok + ((size_t)b * nS + t) * nWD;
        arow1 = tok + ((size_t)b * nS + max(t - 1, 0)) * nWD;
    }
    const float* wrow = redW + (size_t)l * (320 * 640) + (size_t)(cn0 + wlm) * 640;
    float acc[4][4] = {};
    for (int k0 = 0; k0 < 640; k0 += 16) {
        const int k = k0 + alk;
        h16x8 av = {};
        if (rm >= 0) av = (k < 320) ? *(const h16x8*)(arow0 + k)
                                    : *(const h16x8*)(arow1 + (k - 320));
        const float4 wv = *(const float4*)(wrow + k0 + wlk);
        __syncthreads();
        if (tid < 128) {
            #pragma unroll
            for (int j = 0; j < 8; ++j) As[alk + j][alm] = (float)av[j];
        }
        Ws[wlk + 0][wlm] = wv.x; Ws[wlk + 1][wlm] = wv.y;
        Ws[wlk + 2][wlm] = wv.z; Ws[wlk + 3][wlm] = wv.w;
        __syncthreads();
        #pragma unroll
        for (int kk = 0; kk < 16; ++kk) {
            const float4 a4 = *(const float4*)&As[kk][trow << 2];
            const float4 w4 = *(const float4*)&Ws[kk][tcol << 2];
            const float aa[4] = {a4.x, a4.y, a4.z, a4.w};
            const float ww[4] = {w4.x, w4.y, w4.z, w4.w};
            #pragma unroll
            for (int i = 0; i < 4; ++i)
                #pragma unroll
                for (int j = 0; j < 4; ++j)
                    acc[i][j] = fmaf(aa[i], ww[j], acc[i][j]);
        }
    }
    #pragma unroll
    for (int i = 0; i < 4; ++i) {
        const int rr = rows_s[(trow << 2) + i];
        if (rr < 0) continue;
        #pragma unroll
        for (int j = 0; j < 4; ++j) {
            const int cc = cn0 + (tcol << 2) + j;
            comp[(size_t)rr * nWD + cc] = (h16)tanhf(acc[i][j] + redb[l * nWD + cc]);
        }
    }
}

// ---------------- token LSTM scan (cooperative launch for co-residency) ----------------
// 256 blocks x 512 thr; group = 32 blocks sharing batch-group g.
// h-exchange via RELAXED agent atomics (no acquire/release -> no L2 wb/inv);
// Whh fp16 register-resident (32 VGPR/thread), c-state in registers.
__global__ __launch_bounds__(512)
void tok_scan_k(const h16* __restrict__ W16, const h16* __restrict__ gx,
                float* __restrict__ hbuf, h16* __restrict__ tokrec,
                int* __restrict__ bar)
{
    const int blk = blockIdx.x;
    const int g = blk >> 5, jb = blk & 31;
    const int tid = threadIdx.x;
    const int kg = tid & 7, r64 = tid >> 3;
    const int c = r64 >> 4, jl = r64 & 15;
    const int grow = c * nH + (jb << 4) + jl;
    const h16* wrow = W16 + (size_t)grow * nH;
    const int r64u = tid & 63, bu = tid >> 6;
    const int grow_u = (r64u >> 4) * nH + (jb << 4) + (r64u & 15);
    int* slots = bar + g * 64;
    u64t* hq = (u64t*)hbuf;
    __shared__ __align__(16) float hsm[8][nH];
    __shared__ float ps[8][8][65];
    __shared__ float gex[64][9];
    // preload Whh rows into registers: 8 x h16x8 = 64 halfs (thread covers k = i*64 + kg*8)
    h16x8 wreg[8];
    #pragma unroll
    for (int i = 0; i < 8; ++i) wreg[i] = *(const h16x8*)(wrow + (i << 6) + (kg << 3));
    float creg[2] = {0.0f, 0.0f};
    for (int t = 0; t < nS; ++t) {
        if (t == 0) {
            for (int i = tid; i < 8 * nH; i += 512) ((float*)hsm)[i] = 0.0f;
        } else {
            const size_t base = (((size_t)((t - 1) & 1) * BH) + ((size_t)(g << 3) * nH)) >> 1;
            #pragma unroll
            for (int i2 = 0; i2 < 4; ++i2) {
                u64t v = __hip_atomic_load(hq + base + tid + i2 * 512,
                                           __ATOMIC_RELAXED, __HIP_MEMORY_SCOPE_AGENT);
                ((float2*)hsm)[tid + i2 * 512] = __builtin_bit_cast(float2, v);
            }
        }
        __syncthreads();
        const float gxv = (float)gx[(size_t)((t << 6) + (g << 3) + bu) * nG + grow_u];
        float acc[8] = {0.f,0.f,0.f,0.f,0.f,0.f,0.f,0.f};
        #pragma unroll
        for (int i = 0; i < 8; ++i) {
            const int k = (i << 6) + (kg << 3);
            float wf[8];
            #pragma unroll
            for (int j = 0; j < 8; ++j) wf[j] = (float)wreg[i][j];
            #pragma unroll
            for (int b = 0; b < 8; ++b) {
                const float4 h0 = *(const float4*)(&hsm[b][k]);
                const float4 h1 = *(const float4*)(&hsm[b][k + 4]);
                acc[b] = fmaf(wf[0], h0.x, acc[b]); acc[b] = fmaf(wf[1], h0.y, acc[b]);
                acc[b] = fmaf(wf[2], h0.z, acc[b]); acc[b] = fmaf(wf[3], h0.w, acc[b]);
                acc[b] = fmaf(wf[4], h1.x, acc[b]); acc[b] = fmaf(wf[5], h1.y, acc[b]);
                acc[b] = fmaf(wf[6], h1.z, acc[b]); acc[b] = fmaf(wf[7], h1.w, acc[b]);
            }
        }
        #pragma unroll
        for (int b = 0; b < 8; ++b) ps[kg][b][r64] = acc[b];
        __syncthreads();
        float gsum = gxv;
        #pragma unroll
        for (int k2 = 0; k2 < 8; ++k2) gsum += ps[k2][bu][r64u];
        gex[r64u][bu] = gsum;
        __syncthreads();
        if (tid < 64) {
            const int q = tid >> 3, b2 = tid & 7;
            const int jl0 = q << 1;
            float hn2[2];
            #pragma unroll
            for (int u = 0; u < 2; ++u) {
                const int jl2 = jl0 + u;
                const float gi = gex[jl2][b2];
                const float gf = gex[16 + jl2][b2];
                const float gg = gex[32 + jl2][b2];
                const float go = gex[48 + jl2][b2];
                const float cn = sigf(gf) * creg[u] + sigf(gi) * tanhf(gg);
                hn2[u] = sigf(go) * tanhf(cn);
                creg[u] = cn;
            }
            const int bg = (g << 3) + b2, jh = (jb << 4) + jl0;
            float2 hf; hf.x = hn2[0]; hf.y = hn2[1];
            __hip_atomic_store(hq + (((size_t)(t & 1) * BH + (size_t)bg * nH + jh) >> 1),
                               __builtin_bit_cast(u64t, hf),
                               __ATOMIC_RELAXED, __HIP_MEMORY_SCOPE_AGENT);
            h16x2 hp; hp[0] = (h16)hn2[0]; hp[1] = (h16)hn2[1];
            *(h16x2*)(tokrec + (size_t)t * BH + (size_t)bg * nH + jh) = hp;
        }
        if (t + 1 < nS) {
            asm volatile("s_waitcnt vmcnt(0)" ::: "memory");
            __syncthreads();
            if (tid == 0)
                __hip_atomic_store(&slots[jb], t + 1, __ATOMIC_RELAXED, __HIP_MEMORY_SCOPE_AGENT);
            if (tid < 64) {
                while (__hip_atomic_load(&slots[tid & 31], __ATOMIC_RELAXED, __HIP_MEMORY_SCOPE_AGENT) < t + 1)
                    __builtin_amdgcn_s_sleep(1);
            }
            __syncthreads();
        }
    }
}

// ---------------- action scan: two independent LSTM chains ----------------
// 512 blocks x 256 thr; group = (role, g) -> 32 blocks. Same transport as tok_scan.
__global__ __launch_bounds__(256)
void act_scan_k(const h16* __restrict__ sW16, const h16* __restrict__ aW16,
                const h16* __restrict__ stX, const float* __restrict__ acTab,
                const int* __restrict__ actb,
                float* __restrict__ spbuf, float* __restrict__ apbuf,
                h16* __restrict__ hsrec, h16* __restrict__ harec,
                int* __restrict__ bar)
{
    const int blk = blockIdx.x;
    const int role = blk >> 8;              // 0 = stack LSTM, 1 = action LSTM
    const int sub = blk & 255;
    const int g = sub >> 5, jb = sub & 31;
    const int tid = threadIdx.x;
    const int kg = tid & 3, r64 = tid >> 2;
    const int c = r64 >> 4, jl = r64 & 15;
    const int grow = c * nH + (jb << 4) + jl;
    const h16* W16 = role ? aW16 : sW16;
    float* pbuf    = role ? apbuf : spbuf;
    u64t* hq = (u64t*)pbuf;
    const h16* wrow = W16 + (size_t)grow * nH;
    const int r64u = tid & 63, bu0 = (tid >> 6) << 1;
    const int grow_u = (r64u >> 4) * nH + (jb << 4) + (r64u & 15);
    int* slots = bar + (role * 8 + g) * 64;
    __shared__ __align__(16) float hsm[8][nH];
    __shared__ float ps[4][8][65];
    __shared__ float gex[64][9];
    __shared__ int aidx[8];
    // preload Whh rows: 16 x h16x8 = 128 halfs (thread covers k = i*32 + kg*8)
    h16x8 wreg[16];
    #pragma unroll
    for (int i = 0; i < 16; ++i) wreg[i] = *(const h16x8*)(wrow + (i << 5) + (kg << 3));
    float creg[2] = {0.0f, 0.0f};
    for (int t = 0; t < nAc; ++t) {
        if (t == 0) {
            for (int i = tid; i < 8 * nH; i += 256) ((float*)hsm)[i] = 0.0f;
        } else {
            const size_t base = (((size_t)((t - 1) & 1) * BH) + ((size_t)(g << 3) * nH)) >> 1;
            #pragma unroll
            for (int i2 = 0; i2 < 8; ++i2) {
                u64t v = __hip_atomic_load(hq + base + tid + i2 * 256,
                                           __ATOMIC_RELAXED, __HIP_MEMORY_SCOPE_AGENT);
                ((float2*)hsm)[tid + i2 * 256] = __builtin_bit_cast(float2, v);
            }
        }
        if (role && tid < 8) aidx[tid] = actb[((g << 3) + tid) * nAc + t];
        __syncthreads();
        float gpre[2];
        #pragma unroll
        for (int bb = 0; bb < 2; ++bb) {
            if (role) gpre[bb] = acTab[(size_t)aidx[bu0 + bb] * nG + grow_u];
            else      gpre[bb] = (float)stX[(size_t)((t << 6) + (g << 3) + bu0 + bb) * nG + grow_u];
        }
        float acc[8] = {0.f,0.f,0.f,0.f,0.f,0.f,0.f,0.f};
        #pragma unroll
        for (int i = 0; i < 16; ++i) {
            const int k = (i << 5) + (kg << 3);
            float wf[8];
            #pragma unroll
            for (int j = 0; j < 8; ++j) wf[j] = (float)wreg[i][j];
            #pragma unroll
            for (int b = 0; b < 8; ++b) {
                const float4 h0 = *(const float4*)(&hsm[b][k]);
                const float4 h1 = *(const float4*)(&hsm[b][k + 4]);
                acc[b] = fmaf(wf[0], h0.x, acc[b]); acc[b] = fmaf(wf[1], h0.y, acc[b]);
                acc[b] = fmaf(wf[2], h0.z, acc[b]); acc[b] = fmaf(wf[3], h0.w, acc[b]);
                acc[b] = fmaf(wf[4], h1.x, acc[b]); acc[b] = fmaf(wf[5], h1.y, acc[b]);
                acc[b] = fmaf(wf[6], h1.z, acc[b]); acc[b] = fmaf(wf[7], h1.w, acc[b]);
            }
        }
        #pragma unroll
        for (int b = 0; b < 8; ++b) ps[kg][b][r64] = acc[b];
        __syncthreads();
        #pragma unroll
        for (int bb = 0; bb < 2; ++bb) {
            float gsum = gpre[bb];
            #pragma unroll
            for (int k2 = 0; k2 < 4; ++k2) gsum += ps[k2][bu0 + bb][r64u];
            gex[r64u][bu0 + bb] = gsum;
        }
        __syncthreads();
        if (tid < 64) {
            const int q = tid >> 3, b2 = tid & 7;
            const int jl0 = q << 1;
            float hn2[2];
            #pragma unroll
            for (int u = 0; u < 2; ++u) {
                const int jl2 = jl0 + u;
                const float gi = gex[jl2][b2];
                const float gf = gex[16 + jl2][b2];
                const float gg = gex[32 + jl2][b2];
                const float go = gex[48 + jl2][b2];
                const float cn = sigf(gf) * creg[u] + sigf(gi) * tanhf(gg);
                hn2[u] = sigf(go) * tanhf(cn);
                creg[u] = cn;
            }
            const int bg = (g << 3) + b2, jh = (jb << 4) + jl0;
            float2 hf; hf.x = hn2[0]; hf.y = hn2[1];
            __hip_atomic_store(hq + (((size_t)(t & 1) * BH + (size_t)bg * nH + jh) >> 1),
                               __builtin_bit_cast(u64t, hf),
                               __ATOMIC_RELAXED, __HIP_MEMORY_SCOPE_AGENT);
            h16x2 hp; hp[0] = (h16)hn2[0]; hp[1] = (h16)hn2[1];
            h16* rec = role ? (harec + (size_t)t * BH) : (hsrec + (size_t)(t + 2) * BH);
            *(h16x2*)(rec + (size_t)bg * nH + jh) = hp;
        }
        if (t + 1 < nAc) {
            asm volatile("s_waitcnt vmcnt(0)" ::: "memory");
            __syncthreads();
            if (tid == 0)
                __hip_atomic_store(&slots[jb], t + 1, __ATOMIC_RELAXED, __HIP_MEMORY_SCOPE_AGENT);
            if (tid < 64) {
                while (__hip_atomic_load(&slots[tid & 31], __ATOMIC_RELAXED, __HIP_MEMORY_SCOPE_AGENT) < t + 1)
                    __builtin_amdgcn_s_sleep(1);
            }
            __syncthreads();
        }
    }
}

// ---------------- per-(t,b) logits + log-softmax loss ----------------
__global__ __launch_bounds__(128)
void loss_k(const h16* __restrict__ hidden, const float* __restrict__ f2aW,
            const float* __restrict__ f2ab, const int* __restrict__ actb,
            float* __restrict__ losses)
{
    const int r = blockIdx.x;
    const int t = r >> 6, b = r & 63;
    __shared__ __align__(16) float hrow[nH];
    __shared__ float lg[nNA + 1];
    const int tid = threadIdx.x;
    if (tid < 64) {
        const h16x8 v = ((const h16x8*)(hidden + (size_t)r * nH))[tid];
        #pragma unroll
        for (int j = 0; j < 8; ++j) hrow[tid * 8 + j] = (float)v[j];
    }
    __syncthreads();
    if (tid < nNA) {
        const float* wr = f2aW + (size_t)tid * nH;
        float a = f2ab[tid];
        for (int k = 0; k < nH; k += 4) {
            const float4 wv = *(const float4*)(wr + k);
            const float4 hv = *(const float4*)(&hrow[k]);
            a = fmaf(wv.x, hv.x, a); a = fmaf(wv.y, hv.y, a);
            a = fmaf(wv.z, hv.z, a); a = fmaf(wv.w, hv.w, a);
        }
        lg[tid] = a;
    }
    __syncthreads();
    if (tid < 64) {
        float m = -1e30f;
        for (int i = tid; i < nNA; i += 64) m = fmaxf(m, lg[i]);
        #pragma unroll
        for (int o = 32; o > 0; o >>= 1) m = fmaxf(m, __shfl_xor(m, o));
        float s = 0.0f;
        for (int i = tid; i < nNA; i += 64) s += __expf(lg[i] - m);
        #pragma unroll
        for (int o = 32; o > 0; o >>= 1) s += __shfl_xor(s, o);
        if (tid == 0) {
            const int a = actb[b * nAc + t];
            losses[r] = m + logf(s) - lg[a];
        }
    }
}

__global__ __launch_bounds__(256)
void reduce_k(const float* __restrict__ losses, float* __restrict__ out)
{
    __shared__ float sm[256];
    const int tid = threadIdx.x;
    float a = 0.0f;
    for (int i = tid; i < nS * nB; i += 256) a += losses[i];
    sm[tid] = a; __syncthreads();
    for (int s = 128; s > 0; s >>= 1) { if (tid < s) sm[tid] += sm[tid + s]; __syncthreads(); }
    if (tid == 0) out[0] = sm[0] * (1.0f / 16384.0f);
}

// ---------------- launch ----------------
extern "C" void kernel_launch(void* const* d_in, const int* in_sizes, int n_in,
                              void* d_out, int out_size, void* d_ws, size_t ws_size,
                              hipStream_t stream)
{
    const int*   tokb  = (const int*)  d_in[0];
    const int*   posb  = (const int*)  d_in[1];
    const int*   actb  = (const int*)  d_in[3];
    const float* wemb  = (const float*)d_in[4];
    const float* pemb  = (const float*)d_in[5];
    const float* aemb  = (const float*)d_in[6];
    const float* tWih  = (const float*)d_in[7];
    const float* tWhh  = (const float*)d_in[8];
    const float* tb    = (const float*)d_in[9];
    const float* sWih  = (const float*)d_in[10];
    const float* sWhh  = (const float*)d_in[11];
    const float* sb    = (const float*)d_in[12];
    const float* aWih  = (const float*)d_in[13];
    const float* aWhh  = (const float*)d_in[14];
    const float* ab    = (const float*)d_in[15];
    const float* redW  = (const float*)d_in[16];
    const float* redb  = (const float*)d_in[17];
    const float* compW = (const float*)d_in[18];
    const float* compb = (const float*)d_in[19];
    const float* h2fW  = (const float*)d_in[20];
    const float* h2fb  = (const float*)d_in[21];
    const float* f2aW  = (const float*)d_in[22];
    const float* f2ab  = (const float*)d_in[23];

    // ---- workspace carve (~130 MB total) ----
    char* base = (char*)d_ws;
    auto carve = [&](size_t bytes) { char* p = base; base += (bytes + 255) & ~(size_t)255; return p; };
    h16*   tok    = (h16*)  carve((size_t)nB * nS * nWD * 2);        // 10.5 MB
    h16*   Xh     = (h16*)  carve((size_t)nS * nB * nG * 2);         // 32 MB (tokX -> stX -> hidden)
    h16*   comph  = (h16*)  carve((size_t)nS * nB * nWD * 2);        // 10.5 MB
    h16*   stinh  = (h16*)  carve((size_t)nS * BH * 2);              // 16 MB
    h16*   tokrec = (h16*)  carve((size_t)nS * BH * 2);              // 16 MB
    h16*   hsrec  = (h16*)  carve((size_t)(nS + 2) * BH * 2);        // 16.9 MB
    h16*   harec  = (h16*)  carve((size_t)nS * BH * 2);              // 16 MB
    h16*   tW16   = (h16*)  carve((size_t)nG * nH * 2);              // 2 MB
    h16*   sW16   = (h16*)  carve((size_t)nG * nH * 2);              // 2 MB
    h16*   aW16   = (h16*)  carve((size_t)nG * nH * 2);              // 2 MB
    float* acTab  = (float*)carve((size_t)nNA * nG * 4);             // 0.6 MB
    float* hbuf   = (float*)carve((size_t)2 * BH * 4);
    float* spbuf  = (float*)carve((size_t)2 * BH * 4);
    float* apbuf  = (float*)carve((size_t)2 * BH * 4);
    float* losses = (float*)carve((size_t)nS * nB * 4);
    int*   bar_tok  = (int*)carve(8 * 64 * 4);
    int*   bar_act  = (int*)carve(16 * 64 * 4);
    int*   lab      = (int*)carve((size_t)nS * nB * 4);
    int*   counts   = (int*)carve(nLB * 4);
    int*   offs     = (int*)carve((nLB + 1) * 4);
    int*   fill     = (int*)carve(nLB * 4);
    int*   tl_lab   = (int*)carve(320 * 4);
    int*   tl_start = (int*)carve(320 * 4);
    int*   tl_cnt   = (int*)carve(320 * 4);
    int*   ntiles   = (int*)carve(4);
    int*   idxb     = (int*)carve((size_t)nS * nB * 4);

    init_k<<<dim3(256), dim3(256), 0, stream>>>(hsrec, counts, fill, bar_tok, bar_act);
    embed_k<<<dim3(nB * nS), dim3(64), 0, stream>>>(tokb, posb, wemb, pemb, tok);
    actab_k<<<dim3(nNA), dim3(256), 0, stream>>>(aemb, aWih, ab, acTab);
    wcvt_k<<<dim3(1024), dim3(256), 0, stream>>>(tWhh, sWhh, aWhh, tW16, sW16, aW16);
    // tokX = tok @ tok_Wih.T + tok_b  -> Xh
    gemm_k<0,false><<<dim3(256, 32), dim3(256), 0, stream>>>(tWih, tb, tok, nullptr, nullptr, Xh, nWD, nG);
    // label sort + composed
    hist_k<<<dim3(64), dim3(256), 0, stream>>>(actb, lab, counts);
    tiles_k<<<dim3(1), dim3(64), 0, stream>>>(counts, offs, tl_lab, tl_start, tl_cnt, ntiles);
    scatter_k<<<dim3(64), dim3(256), 0, stream>>>(lab, offs, fill, idxb);
    comp_gemm_k<<<dim3(304, 5), dim3(256), 0, stream>>>(tok, redW, redb, idxb, tl_lab, tl_start, tl_cnt, ntiles, comph);
    // token scan (cooperative launch for co-residency; relaxed-atomic transport inside)
    {
        const h16* a0 = tW16; const h16* a1 = Xh; float* a2 = hbuf; h16* a3 = tokrec; int* a4 = bar_tok;
        void* args[] = {&a0, &a1, &a2, &a3, &a4};
        hipLaunchCooperativeKernel((const void*)tok_scan_k, dim3(256), dim3(512), args, 0, stream);
    }
    // st_in = tokrec + composed @ comp_W.T + comp_b -> stinh
    gemm_k<4,false><<<dim3(256, 8), dim3(256), 0, stream>>>(compW, compb, comph, tokrec, nullptr, stinh, nWD, nH);
    // stX = st_in @ st_Wih.T + st_b -> Xh (tokX dead)
    gemm_k<1,false><<<dim3(256, 32), dim3(256), 0, stream>>>(sWih, sb, stinh, nullptr, nullptr, Xh, nH, nG);
    // action scan (cooperative): stack chain + action chain concurrently
    {
        const h16* a0 = sW16; const h16* a1 = aW16; const h16* a2 = Xh; const float* a3 = acTab;
        const int* a4 = actb; float* a5 = spbuf; float* a6 = apbuf;
        h16* a7 = hsrec; h16* a8 = harec; int* a9 = bar_act;
        void* args[] = {&a0, &a1, &a2, &a3, &a4, &a5, &a6, &a7, &a8, &a9};
        hipLaunchCooperativeKernel((const void*)act_scan_k, dim3(512), dim3(256), args, 0, stream);
    }
    // hidden = relu(feat @ h2f_W.T + h2f_b) -> Xh (stX dead)
    gemm_k<3,true><<<dim3(256, 8), dim3(256), 0, stream>>>(h2fW, h2fb, hsrec, tokrec, harec, Xh, nFH, nH);
    loss_k<<<dim3(nS * nB), dim3(128), 0, stream>>>(Xh, f2aW, f2ab, actb, losses);
    reduce_k<<<dim3(1), dim3(256), 0, stream>>>(losses, (float*)d_out);
}

// Round 5
// 4811.596 us; speedup vs baseline: 6.0162x; 1.2164x over previous
//
#include <hip/hip_runtime.h>
#include <math.h>

constexpr int nB = 64, nS = 256, nAc = 256, nH = 512, nG = 2048;
constexpr int nWD = 320, nNA = 75, nLB = 48, nFH = 2560;
constexpr int BH = nB * nH; // 32768

typedef _Float16 h16;
typedef _Float16 h16x8 __attribute__((ext_vector_type(8)));
typedef _Float16 h16x4 __attribute__((ext_vector_type(4)));
typedef _Float16 h16x2 __attribute__((ext_vector_type(2)));
typedef unsigned long long u64t;

__device__ __forceinline__ float sigf(float x) { return 1.0f / (1.0f + __expf(-x)); }

#if __has_builtin(__builtin_amdgcn_fdot2)
#define FDOT2(a, b, c) __builtin_amdgcn_fdot2((a), (b), (c), false)
#else
__device__ __forceinline__ float FDOT2(h16x2 a, h16x2 b, float c) {
    return c + (float)a[0] * (float)b[0] + (float)a[1] * (float)b[1];
}
#endif

// ---------------- init: zero hsrec prefix + sort counters ----------------
__global__ void init_k(h16* __restrict__ hsrec, int* __restrict__ counts, int* __restrict__ fill)
{
    int i = blockIdx.x * 256 + threadIdx.x;
    if (i < 2 * BH) hsrec[i] = (h16)0.0f;
    if (i < nLB) { counts[i] = 0; fill[i] = 0; }
}

// ---------------- weight fp32 -> fp16 conversion (Whh x3) ----------------
__global__ __launch_bounds__(256)
void wcvt_k(const float* __restrict__ w0, const float* __restrict__ w1, const float* __restrict__ w2,
            h16* __restrict__ o0, h16* __restrict__ o1, h16* __restrict__ o2)
{
    const int i = blockIdx.x * 256 + threadIdx.x;
    {
        const float4 a = ((const float4*)w0)[i];
        h16x4 v; v[0]=(h16)a.x; v[1]=(h16)a.y; v[2]=(h16)a.z; v[3]=(h16)a.w;
        ((h16x4*)o0)[i] = v;
    }
    {
        const float4 a = ((const float4*)w1)[i];
        h16x4 v; v[0]=(h16)a.x; v[1]=(h16)a.y; v[2]=(h16)a.z; v[3]=(h16)a.w;
        ((h16x4*)o1)[i] = v;
    }
    {
        const float4 a = ((const float4*)w2)[i];
        h16x4 v; v[0]=(h16)a.x; v[1]=(h16)a.y; v[2]=(h16)a.z; v[3]=(h16)a.w;
        ((h16x4*)o2)[i] = v;
    }
}

// ---------------- embedding gather -> tok fp16 [b][s][0:320] ----------------
__global__ __launch_bounds__(64)
void embed_k(const int* __restrict__ tokb, const int* __restrict__ posb,
             const float* __restrict__ wemb, const float* __restrict__ pemb,
             h16* __restrict__ tok)
{
    const int r = blockIdx.x;            // b*nS + s
    const int tid = threadIdx.x;
    const int tk = tokb[r], pp = posb[r];
    h16x8* d = (h16x8*)(tok + (size_t)r * nWD);
    if (tid < 32) {
        const float4* sw = (const float4*)(wemb + (size_t)tk * 256);
        const float4 a = sw[2 * tid], b = sw[2 * tid + 1];
        h16x8 o;
        o[0]=(h16)a.x; o[1]=(h16)a.y; o[2]=(h16)a.z; o[3]=(h16)a.w;
        o[4]=(h16)b.x; o[5]=(h16)b.y; o[6]=(h16)b.z; o[7]=(h16)b.w;
        d[tid] = o;
    } else if (tid < 40) {
        const int q = tid - 32;
        const float4* sp = (const float4*)(pemb + (size_t)pp * 64);
        const float4 a = sp[2 * q], b = sp[2 * q + 1];
        h16x8 o;
        o[0]=(h16)a.x; o[1]=(h16)a.y; o[2]=(h16)a.z; o[3]=(h16)a.w;
        o[4]=(h16)b.x; o[5]=(h16)b.y; o[6]=(h16)b.z; o[7]=(h16)b.w;
        d[32 + q] = o;
    }
}

// ---------------- action-gate table: acTab[a][j] = aemb[a]·aWih[j] + ab[j] ----------------
__global__ __launch_bounds__(256)
void actab_k(const float* __restrict__ aemb, const float* __restrict__ aWih,
             const float* __restrict__ ab, float* __restrict__ acTab)
{
    const int a = blockIdx.x;            // 0..74
    __shared__ float ae[64];
    const int tid = threadIdx.x;
    if (tid < 64) ae[tid] = aemb[a * 64 + tid];
    __syncthreads();
    for (int j = tid; j < nG; j += 256) {
        const float* wr = aWih + (size_t)j * 64;
        float s = ab[j];
        #pragma unroll
        for (int k = 0; k < 64; k += 4) {
            const float4 w = *(const float4*)(wr + k);
            s = fmaf(w.x, ae[k], s);     s = fmaf(w.y, ae[k + 1], s);
            s = fmaf(w.z, ae[k + 2], s); s = fmaf(w.w, ae[k + 3], s);
        }
        acTab[(size_t)a * nG + j] = s;
    }
}

// ---------------- fp16-in / fp16-out GEMM ----------------
template<int MODE, bool RELU>
__global__ __launch_bounds__(256)
void gemm_k(const float* __restrict__ Wm, const float* __restrict__ bias,
            const h16* __restrict__ A0, const h16* __restrict__ A1,
            const h16* __restrict__ A2, h16* __restrict__ C, int Ktot, int ldC)
{
    const int bm = blockIdx.x << 6, bn = blockIdx.y << 6;
    const int tid = threadIdx.x;
    const int alm = tid >> 1, alk = (tid & 1) << 3;
    const int wlm = tid >> 2, wlk = (tid & 3) << 2;
    const int trow = tid >> 4, tcol = tid & 15;
    __shared__ __align__(16) float As[16][68];
    __shared__ __align__(16) float Ws[16][68];
    const int r = bm + alm;
    const h16* arow = nullptr;
    if (MODE == 0) { const int b = r & 63, s = r >> 6; arow = A0 + ((size_t)b * nS + s) * nWD; }
    if (MODE == 1) { arow = A0 + (size_t)r * nH; }
    if (MODE == 4) { arow = A0 + (size_t)r * nWD; }
    const float* wrow = Wm + (size_t)(bn + wlm) * Ktot;
    float acc[4][4] = {};
    for (int k0 = 0; k0 < Ktot; k0 += 16) {
        h16x8 av;
        if (tid < 128) {
            if (MODE == 3) {
                const int p = k0 >> 9;
                const h16* base = (p == 0) ? A0 + 2 * BH : (p == 1) ? A0 + BH
                                : (p == 2) ? A0 : (p == 3) ? A1 : A2;
                av = *(const h16x8*)(base + (size_t)r * nH + (k0 & 511) + alk);
            } else {
                av = *(const h16x8*)(arow + k0 + alk);
            }
        }
        const float4 wv = *(const float4*)(wrow + k0 + wlk);
        __syncthreads();
        if (tid < 128) {
            #pragma unroll
            for (int j = 0; j < 8; ++j) As[alk + j][alm] = (float)av[j];
        }
        Ws[wlk + 0][wlm] = wv.x; Ws[wlk + 1][wlm] = wv.y;
        Ws[wlk + 2][wlm] = wv.z; Ws[wlk + 3][wlm] = wv.w;
        __syncthreads();
        #pragma unroll
        for (int kk = 0; kk < 16; ++kk) {
            const float4 a4 = *(const float4*)&As[kk][trow << 2];
            const float4 w4 = *(const float4*)&Ws[kk][tcol << 2];
            const float aa[4] = {a4.x, a4.y, a4.z, a4.w};
            const float ww[4] = {w4.x, w4.y, w4.z, w4.w};
            #pragma unroll
            for (int i = 0; i < 4; ++i)
                #pragma unroll
                for (int j = 0; j < 4; ++j)
                    acc[i][j] = fmaf(aa[i], ww[j], acc[i][j]);
        }
    }
    #pragma unroll
    for (int i = 0; i < 4; ++i) {
        const int rr = bm + (trow << 2) + i;
        const int cc = bn + (tcol << 2);
        h16x4 v;
        #pragma unroll
        for (int j = 0; j < 4; ++j) {
            float x = acc[i][j] + bias[cc + j];
            if (MODE == 4) x += (float)A1[(size_t)rr * nH + cc + j];
            if (RELU) x = fmaxf(x, 0.0f);
            v[j] = (h16)x;
        }
        *(h16x4*)(C + (size_t)rr * ldC + cc) = v;
    }
}

// ---------------- label sort for red_W batched GEMM ----------------
__global__ void hist_k(const int* __restrict__ actb, int* __restrict__ lab, int* __restrict__ counts)
{
    const int r = blockIdx.x * 256 + threadIdx.x;
    const int t = r >> 6, b = r & 63;
    const int a = actb[b * nAc + t];
    const int l = a % nLB;
    lab[r] = l;
    atomicAdd(&counts[l], 1);
}

__global__ void tiles_k(const int* __restrict__ counts, int* __restrict__ offs,
                        int* __restrict__ tl_lab, int* __restrict__ tl_start,
                        int* __restrict__ tl_cnt, int* __restrict__ ntiles)
{
    if (blockIdx.x == 0 && threadIdx.x == 0) {
        int o = 0, nt = 0;
        for (int l = 0; l < nLB; ++l) {
            offs[l] = o;
            const int c = counts[l];
            for (int s0 = 0; s0 < c; s0 += 64) {
                tl_lab[nt] = l; tl_start[nt] = o + s0; tl_cnt[nt] = min(64, c - s0); ++nt;
            }
            o += c;
        }
        offs[nLB] = o;
        ntiles[0] = nt;
    }
}

__global__ void scatter_k(const int* __restrict__ lab, const int* __restrict__ offs,
                          int* __restrict__ fill, int* __restrict__ idx)
{
    const int r = blockIdx.x * 256 + threadIdx.x;
    const int l = lab[r];
    const int pos = offs[l] + atomicAdd(&fill[l], 1);
    idx[pos] = r;
}

// composed[r][i] = tanh( pair(r)·red_W[l][i][:] + red_b[l][i] ), rows grouped by label
__global__ __launch_bounds__(256)
void comp_gemm_k(const h16* __restrict__ tok, const float* __restrict__ redW,
                 const float* __restrict__ redb, const int* __restrict__ idx,
                 const int* __restrict__ tl_lab, const int* __restrict__ tl_start,
                 const int* __restrict__ tl_cnt, const int* __restrict__ ntiles,
                 h16* __restrict__ comp)
{
    const int tile = blockIdx.x;
    if (tile >= ntiles[0]) return;
    const int cn0 = blockIdx.y << 6;
    const int l = tl_lab[tile], rst = tl_start[tile], mrows = tl_cnt[tile];
    __shared__ int rows_s[64];
    __shared__ __align__(16) float As[16][68];
    __shared__ __align__(16) float Ws[16][68];
    const int tid = threadIdx.x;
    if (tid < 64) rows_s[tid] = (tid < mrows) ? idx[rst + tid] : -1;
    __syncthreads();
    const int alm = tid >> 1, alk = (tid & 1) << 3;
    const int wlm = tid >> 2, wlk = (tid & 3) << 2;
    const int trow = tid >> 4, tcol = tid & 15;
    const int rm = (tid < 128) ? rows_s[alm] : -1;
    const h16* arow0 = tok;
    const h16* arow1 = tok;
    if (rm >= 0) {
        const int b = rm & 63, t = rm >> 6;
        arow0 = tok + ((size_t)b * nS + t) * nWD;
        arow1 = tok + ((size_t)b * nS + max(t - 1, 0)) * nWD;
    }
    const float* wrow = redW + (size_t)l * (320 * 640) + (size_t)(cn0 + wlm) * 640;
    float acc[4][4] = {};
    for (int k0 = 0; k0 < 640; k0 += 16) {
        const int k = k0 + alk;
        h16x8 av = {};
        if (rm >= 0) av = (k < 320) ? *(const h16x8*)(arow0 + k)
                                    : *(const h16x8*)(arow1 + (k - 320));
        const float4 wv = *(const float4*)(wrow + k0 + wlk);
        __syncthreads();
        if (tid < 128) {
            #pragma unroll
            for (int j = 0; j < 8; ++j) As[alk + j][alm] = (float)av[j];
        }
        Ws[wlk + 0][wlm] = wv.x; Ws[wlk + 1][wlm] = wv.y;
        Ws[wlk + 2][wlm] = wv.z; Ws[wlk + 3][wlm] = wv.w;
        __syncthreads();
        #pragma unroll
        for (int kk = 0; kk < 16; ++kk) {
            const float4 a4 = *(const float4*)&As[kk][trow << 2];
            const float4 w4 = *(const float4*)&Ws[kk][tcol << 2];
            const float aa[4] = {a4.x, a4.y, a4.z, a4.w};
            const float ww[4] = {w4.x, w4.y, w4.z, w4.w};
            #pragma unroll
            for (int i = 0; i < 4; ++i)
                #pragma unroll
                for (int j = 0; j < 4; ++j)
                    acc[i][j] = fmaf(aa[i], ww[j], acc[i][j]);
        }
    }
    #pragma unroll
    for (int i = 0; i < 4; ++i) {
        const int rr = rows_s[(trow << 2) + i];
        if (rr < 0) continue;
        #pragma unroll
        for (int j = 0; j < 4; ++j) {
            const int cc = cn0 + (tcol << 2) + j;
            comp[(size_t)rr * nWD + cc] = (h16)tanhf(acc[i][j] + redb[l * nWD + cc]);
        }
    }
}

// =================== scan kernels: stamped-word transport ===================
// Publish: u64 { hi32 = step+1, lo32 = h16x2 } relaxed agent atomics, depth-2
// ping-pong. Readers poll their own 8 words (exact stamp match -> replay-safe),
// no flags, no vmcnt(0) drain; rec stores issued after publish (off crit path).
// Compute: Whh fp16 in VGPRs, v_dot2_f32_f16, 2 rows x 64-k per thread; hsm
// reads are wave-uniform (LDS broadcast).

// ---------------- token LSTM scan: 256 blocks x 256 thr ----------------
__global__ __launch_bounds__(256)
void tok_scan_k(const h16* __restrict__ W16, const h16* __restrict__ gx,
                u64t* __restrict__ hq, h16* __restrict__ tokrec)
{
    const int blk = blockIdx.x;
    const int g = blk >> 5, jb = blk & 31;
    const int tid = threadIdx.x;
    const int r2 = tid & 31, ks = tid >> 5;         // row-pair, k-slice(64)
    const int c0 = r2 >> 3, jlw = (r2 & 7) << 1;
    const int row0 = (c0 << 4) + jlw;               // = 2*r2
    const int rrow = tid & 63, bq = tid >> 6;       // reduction assignment
    const int growR = ((rrow >> 4) << 9) + (jb << 4) + (rrow & 15);
    __shared__ __align__(16) h16 hsm[8][nH];        // 8 KB
    __shared__ float ps[8][8][64];                  // 16 KB
    __shared__ float gex[64][9];
    // preload W rows (2 x 64 halfs)
    const h16* w0p = W16 + (size_t)(c0 * nH + (jb << 4) + jlw) * nH + (ks << 6);
    h16x8 wreg[2][8];
    #pragma unroll
    for (int i = 0; i < 8; ++i) {
        wreg[0][i] = *(const h16x8*)(w0p + (i << 3));
        wreg[1][i] = *(const h16x8*)(w0p + nH + (i << 3));
    }
    float creg[2] = {0.0f, 0.0f};
    for (int t = 0; t < nS; ++t) {
        // gx prefetch (independent of h)
        float gp[2];
        #pragma unroll
        for (int u = 0; u < 2; ++u) {
            const int b = (bq << 1) + u;
            gp[u] = (float)gx[(size_t)((t << 6) + (g << 3) + b) * nG + growR];
        }
        // phase 1: h into hsm
        if (t == 0) {
            #pragma unroll
            for (int i2 = 0; i2 < 8; ++i2) ((unsigned*)hsm)[(i2 << 8) + tid] = 0;
        } else {
            const int want = t;
            const size_t base = (size_t)((t - 1) & 1) * 16384 + ((size_t)(g << 3) << 8);
            u64t v[8];
            #pragma unroll
            for (int i2 = 0; i2 < 8; ++i2)
                v[i2] = __hip_atomic_load(hq + base + (i2 << 8) + tid, __ATOMIC_RELAXED, __HIP_MEMORY_SCOPE_AGENT);
            #pragma unroll
            for (int i2 = 0; i2 < 8; ++i2) {
                while ((int)(v[i2] >> 32) != want) {
                    __builtin_amdgcn_s_sleep(1);
                    v[i2] = __hip_atomic_load(hq + base + (i2 << 8) + tid, __ATOMIC_RELAXED, __HIP_MEMORY_SCOPE_AGENT);
                }
                ((unsigned*)hsm)[(i2 << 8) + tid] = (unsigned)v[i2];
            }
        }
        __syncthreads();
        // phase 2: dot2 partial sums
        float acc0[8] = {0,0,0,0,0,0,0,0}, acc1[8] = {0,0,0,0,0,0,0,0};
        #pragma unroll
        for (int b = 0; b < 8; ++b) {
            #pragma unroll
            for (int i = 0; i < 8; ++i) {
                h16x8 hv = *(const h16x8*)(&hsm[b][(ks << 6) + (i << 3)]);
                const h16x2* hp = (const h16x2*)&hv;
                const h16x2* wa = (const h16x2*)&wreg[0][i];
                const h16x2* wb = (const h16x2*)&wreg[1][i];
                #pragma unroll
                for (int p = 0; p < 4; ++p) {
                    acc0[b] = FDOT2(hp[p], wa[p], acc0[b]);
                    acc1[b] = FDOT2(hp[p], wb[p], acc1[b]);
                }
            }
        }
        #pragma unroll
        for (int b = 0; b < 8; ++b) {
            float2 pv; pv.x = acc0[b]; pv.y = acc1[b];
            *(float2*)&ps[ks][b][row0] = pv;
        }
        __syncthreads();
        // phase 3: reduce + gx
        #pragma unroll
        for (int u = 0; u < 2; ++u) {
            const int b = (bq << 1) + u;
            float s = gp[u];
            #pragma unroll
            for (int k2 = 0; k2 < 8; ++k2) s += ps[k2][b][rrow];
            gex[rrow][b] = s;
        }
        __syncthreads();
        // phase 4: gates -> h, publish stamped word, rec store after
        if (tid < 64) {
            const int q = tid >> 3, b2 = tid & 7, jl0 = q << 1;
            float hn[2];
            #pragma unroll
            for (int u = 0; u < 2; ++u) {
                const int jl = jl0 + u;
                const float gi = gex[jl][b2], gf = gex[16 + jl][b2];
                const float gg = gex[32 + jl][b2], go = gex[48 + jl][b2];
                const float cn = sigf(gf) * creg[u] + sigf(gi) * tanhf(gg);
                hn[u] = sigf(go) * tanhf(cn);
                creg[u] = cn;
            }
            const int bg = (g << 3) + b2;
            h16x2 hp; hp[0] = (h16)hn[0]; hp[1] = (h16)hn[1];
            const unsigned pay = __builtin_bit_cast(unsigned, hp);
            const u64t word = ((u64t)(unsigned)(t + 1) << 32) | pay;
            __hip_atomic_store(hq + (size_t)(t & 1) * 16384 + ((size_t)bg << 8) + (jb << 3) + q,
                               word, __ATOMIC_RELAXED, __HIP_MEMORY_SCOPE_AGENT);
            *(h16x2*)(tokrec + (size_t)t * BH + (size_t)bg * nH + (jb << 4) + jl0) = hp;
        }
    }
}

// ---------------- action scan: 512 blocks x 256 thr (2 roles) ----------------
__global__ __launch_bounds__(256)
void act_scan_k(const h16* __restrict__ sW16, const h16* __restrict__ aW16,
                const h16* __restrict__ stX, const float* __restrict__ acTab,
                const int* __restrict__ actb,
                u64t* __restrict__ sq, u64t* __restrict__ aq,
                h16* __restrict__ hsrec, h16* __restrict__ harec)
{
    const int blk = blockIdx.x;
    const int role = blk >> 8;
    const int sub = blk & 255;
    const int g = sub >> 5, jb = sub & 31;
    const int tid = threadIdx.x;
    const int r2 = tid & 31, ks = tid >> 5;
    const int c0 = r2 >> 3, jlw = (r2 & 7) << 1;
    const int row0 = (c0 << 4) + jlw;
    const int rrow = tid & 63, bq = tid >> 6;
    const int growR = ((rrow >> 4) << 9) + (jb << 4) + (rrow & 15);
    const h16* W16 = role ? aW16 : sW16;
    u64t* hq = role ? aq : sq;
    __shared__ __align__(16) h16 hsm[8][nH];
    __shared__ float ps[8][8][64];
    __shared__ float gex[64][9];
    const h16* w0p = W16 + (size_t)(c0 * nH + (jb << 4) + jlw) * nH + (ks << 6);
    h16x8 wreg[2][8];
    #pragma unroll
    for (int i = 0; i < 8; ++i) {
        wreg[0][i] = *(const h16x8*)(w0p + (i << 3));
        wreg[1][i] = *(const h16x8*)(w0p + nH + (i << 3));
    }
    float creg[2] = {0.0f, 0.0f};
    for (int t = 0; t < nAc; ++t) {
        float gp[2];
        #pragma unroll
        for (int u = 0; u < 2; ++u) {
            const int b = (bq << 1) + u;
            if (role) {
                const int a = actb[((g << 3) + b) * nAc + t];
                gp[u] = acTab[(size_t)a * nG + growR];
            } else {
                gp[u] = (float)stX[(size_t)((t << 6) + (g << 3) + b) * nG + growR];
            }
        }
        if (t == 0) {
            #pragma unroll
            for (int i2 = 0; i2 < 8; ++i2) ((unsigned*)hsm)[(i2 << 8) + tid] = 0;
        } else {
            const int want = t;
            const size_t base = (size_t)((t - 1) & 1) * 16384 + ((size_t)(g << 3) << 8);
            u64t v[8];
            #pragma unroll
            for (int i2 = 0; i2 < 8; ++i2)
                v[i2] = __hip_atomic_load(hq + base + (i2 << 8) + tid, __ATOMIC_RELAXED, __HIP_MEMORY_SCOPE_AGENT);
            #pragma unroll
            for (int i2 = 0; i2 < 8; ++i2) {
                while ((int)(v[i2] >> 32) != want) {
                    __builtin_amdgcn_s_sleep(1);
                    v[i2] = __hip_atomic_load(hq + base + (i2 << 8) + tid, __ATOMIC_RELAXED, __HIP_MEMORY_SCOPE_AGENT);
                }
                ((unsigned*)hsm)[(i2 << 8) + tid] = (unsigned)v[i2];
            }
        }
        __syncthreads();
        float acc0[8] = {0,0,0,0,0,0,0,0}, acc1[8] = {0,0,0,0,0,0,0,0};
        #pragma unroll
        for (int b = 0; b < 8; ++b) {
            #pragma unroll
            for (int i = 0; i < 8; ++i) {
                h16x8 hv = *(const h16x8*)(&hsm[b][(ks << 6) + (i << 3)]);
                const h16x2* hp = (const h16x2*)&hv;
                const h16x2* wa = (const h16x2*)&wreg[0][i];
                const h16x2* wb = (const h16x2*)&wreg[1][i];
                #pragma unroll
                for (int p = 0; p < 4; ++p) {
                    acc0[b] = FDOT2(hp[p], wa[p], acc0[b]);
                    acc1[b] = FDOT2(hp[p], wb[p], acc1[b]);
                }
            }
        }
        #pragma unroll
        for (int b = 0; b < 8; ++b) {
            float2 pv; pv.x = acc0[b]; pv.y = acc1[b];
            *(float2*)&ps[ks][b][row0] = pv;
        }
        __syncthreads();
        #pragma unroll
        for (int u = 0; u < 2; ++u) {
            const int b = (bq << 1) + u;
            float s = gp[u];
            #pragma unroll
            for (int k2 = 0; k2 < 8; ++k2) s += ps[k2][b][rrow];
            gex[rrow][b] = s;
        }
        __syncthreads();
        if (tid < 64) {
            const int q = tid >> 3, b2 = tid & 7, jl0 = q << 1;
            float hn[2];
            #pragma unroll
            for (int u = 0; u < 2; ++u) {
                const int jl = jl0 + u;
                const float gi = gex[jl][b2], gf = gex[16 + jl][b2];
                const float gg = gex[32 + jl][b2], go = gex[48 + jl][b2];
                const float cn = sigf(gf) * creg[u] + sigf(gi) * tanhf(gg);
                hn[u] = sigf(go) * tanhf(cn);
                creg[u] = cn;
            }
            const int bg = (g << 3) + b2;
            h16x2 hp; hp[0] = (h16)hn[0]; hp[1] = (h16)hn[1];
            const unsigned pay = __builtin_bit_cast(unsigned, hp);
            const u64t word = ((u64t)(unsigned)(t + 1) << 32) | pay;
            __hip_atomic_store(hq + (size_t)(t & 1) * 16384 + ((size_t)bg << 8) + (jb << 3) + q,
                               word, __ATOMIC_RELAXED, __HIP_MEMORY_SCOPE_AGENT);
            h16* rec = role ? (harec + (size_t)t * BH) : (hsrec + (size_t)(t + 2) * BH);
            *(h16x2*)(rec + (size_t)bg * nH + (jb << 4) + jl0) = hp;
        }
    }
}

// ---------------- per-(t,b) logits + log-softmax loss ----------------
__global__ __launch_bounds__(128)
void loss_k(const h16* __restrict__ hidden, const float* __restrict__ f2aW,
            const float* __restrict__ f2ab, const int* __restrict__ actb,
            float* __restrict__ losses)
{
    const int r = blockIdx.x;
    const int t = r >> 6, b = r & 63;
    __shared__ __align__(16) float hrow[nH];
    __shared__ float lg[nNA + 1];
    const int tid = threadIdx.x;
    if (tid < 64) {
        const h16x8 v = ((const h16x8*)(hidden + (size_t)r * nH))[tid];
        #pragma unroll
        for (int j = 0; j < 8; ++j) hrow[tid * 8 + j] = (float)v[j];
    }
    __syncthreads();
    if (tid < nNA) {
        const float* wr = f2aW + (size_t)tid * nH;
        float a = f2ab[tid];
        for (int k = 0; k < nH; k += 4) {
            const float4 wv = *(const float4*)(wr + k);
            const float4 hv = *(const float4*)(&hrow[k]);
            a = fmaf(wv.x, hv.x, a); a = fmaf(wv.y, hv.y, a);
            a = fmaf(wv.z, hv.z, a); a = fmaf(wv.w, hv.w, a);
        }
        lg[tid] = a;
    }
    __syncthreads();
    if (tid < 64) {
        float m = -1e30f;
        for (int i = tid; i < nNA; i += 64) m = fmaxf(m, lg[i]);
        #pragma unroll
        for (int o = 32; o > 0; o >>= 1) m = fmaxf(m, __shfl_xor(m, o));
        float s = 0.0f;
        for (int i = tid; i < nNA; i += 64) s += __expf(lg[i] - m);
        #pragma unroll
        for (int o = 32; o > 0; o >>= 1) s += __shfl_xor(s, o);
        if (tid == 0) {
            const int a = actb[b * nAc + t];
            losses[r] = m + logf(s) - lg[a];
        }
    }
}

__global__ __launch_bounds__(256)
void reduce_k(const float* __restrict__ losses, float* __restrict__ out)
{
    __shared__ float sm[256];
    const int tid = threadIdx.x;
    float a = 0.0f;
    for (int i = tid; i < nS * nB; i += 256) a += losses[i];
    sm[tid] = a; __syncthreads();
    for (int s = 128; s > 0; s >>= 1) { if (tid < s) sm[tid] += sm[tid + s]; __syncthreads(); }
    if (tid == 0) out[0] = sm[0] * (1.0f / 16384.0f);
}

// ---------------- launch ----------------
extern "C" void kernel_launch(void* const* d_in, const int* in_sizes, int n_in,
                              void* d_out, int out_size, void* d_ws, size_t ws_size,
                              hipStream_t stream)
{
    const int*   tokb  = (const int*)  d_in[0];
    const int*   posb  = (const int*)  d_in[1];
    const int*   actb  = (const int*)  d_in[3];
    const float* wemb  = (const float*)d_in[4];
    const float* pemb  = (const float*)d_in[5];
    const float* aemb  = (const float*)d_in[6];
    const float* tWih  = (const float*)d_in[7];
    const float* tWhh  = (const float*)d_in[8];
    const float* tb    = (const float*)d_in[9];
    const float* sWih  = (const float*)d_in[10];
    const float* sWhh  = (const float*)d_in[11];
    const float* sb    = (const float*)d_in[12];
    const float* aWih  = (const float*)d_in[13];
    const float* aWhh  = (const float*)d_in[14];
    const float* ab    = (const float*)d_in[15];
    const float* redW  = (const float*)d_in[16];
    const float* redb  = (const float*)d_in[17];
    const float* compW = (const float*)d_in[18];
    const float* compb = (const float*)d_in[19];
    const float* h2fW  = (const float*)d_in[20];
    const float* h2fb  = (const float*)d_in[21];
    const float* f2aW  = (const float*)d_in[22];
    const float* f2ab  = (const float*)d_in[23];

    // ---- workspace carve ----
    char* base = (char*)d_ws;
    auto carve = [&](size_t bytes) { char* p = base; base += (bytes + 255) & ~(size_t)255; return p; };
    h16*   tok    = (h16*)  carve((size_t)nB * nS * nWD * 2);
    h16*   Xh     = (h16*)  carve((size_t)nS * nB * nG * 2);
    h16*   comph  = (h16*)  carve((size_t)nS * nB * nWD * 2);
    h16*   stinh  = (h16*)  carve((size_t)nS * BH * 2);
    h16*   tokrec = (h16*)  carve((size_t)nS * BH * 2);
    h16*   hsrec  = (h16*)  carve((size_t)(nS + 2) * BH * 2);
    h16*   harec  = (h16*)  carve((size_t)nS * BH * 2);
    h16*   tW16   = (h16*)  carve((size_t)nG * nH * 2);
    h16*   sW16   = (h16*)  carve((size_t)nG * nH * 2);
    h16*   aW16   = (h16*)  carve((size_t)nG * nH * 2);
    float* acTab  = (float*)carve((size_t)nNA * nG * 4);
    u64t*  hbuf   = (u64t*) carve((size_t)2 * 16384 * 8);   // tok h transport
    u64t*  spbuf  = (u64t*) carve((size_t)2 * 16384 * 8);   // stack h transport
    u64t*  apbuf  = (u64t*) carve((size_t)2 * 16384 * 8);   // action h transport
    float* losses = (float*)carve((size_t)nS * nB * 4);
    int*   lab      = (int*)carve((size_t)nS * nB * 4);
    int*   counts   = (int*)carve(nLB * 4);
    int*   offs     = (int*)carve((nLB + 1) * 4);
    int*   fill     = (int*)carve(nLB * 4);
    int*   tl_lab   = (int*)carve(320 * 4);
    int*   tl_start = (int*)carve(320 * 4);
    int*   tl_cnt   = (int*)carve(320 * 4);
    int*   ntiles   = (int*)carve(4);
    int*   idxb     = (int*)carve((size_t)nS * nB * 4);

    init_k<<<dim3(256), dim3(256), 0, stream>>>(hsrec, counts, fill);
    embed_k<<<dim3(nB * nS), dim3(64), 0, stream>>>(tokb, posb, wemb, pemb, tok);
    actab_k<<<dim3(nNA), dim3(256), 0, stream>>>(aemb, aWih, ab, acTab);
    wcvt_k<<<dim3(1024), dim3(256), 0, stream>>>(tWhh, sWhh, aWhh, tW16, sW16, aW16);
    gemm_k<0,false><<<dim3(256, 32), dim3(256), 0, stream>>>(tWih, tb, tok, nullptr, nullptr, Xh, nWD, nG);
    hist_k<<<dim3(64), dim3(256), 0, stream>>>(actb, lab, counts);
    tiles_k<<<dim3(1), dim3(64), 0, stream>>>(counts, offs, tl_lab, tl_start, tl_cnt, ntiles);
    scatter_k<<<dim3(64), dim3(256), 0, stream>>>(lab, offs, fill, idxb);
    comp_gemm_k<<<dim3(304, 5), dim3(256), 0, stream>>>(tok, redW, redb, idxb, tl_lab, tl_start, tl_cnt, ntiles, comph);
    // token scan (cooperative for co-residency)
    {
        const h16* a0 = tW16; const h16* a1 = Xh; u64t* a2 = hbuf; h16* a3 = tokrec;
        void* args[] = {&a0, &a1, &a2, &a3};
        hipLaunchCooperativeKernel((const void*)tok_scan_k, dim3(256), dim3(256), args, 0, stream);
    }
    gemm_k<4,false><<<dim3(256, 8), dim3(256), 0, stream>>>(compW, compb, comph, tokrec, nullptr, stinh, nWD, nH);
    gemm_k<1,false><<<dim3(256, 32), dim3(256), 0, stream>>>(sWih, sb, stinh, nullptr, nullptr, Xh, nH, nG);
    // action scan (cooperative): both chains concurrently
    {
        const h16* a0 = sW16; const h16* a1 = aW16; const h16* a2 = Xh; const float* a3 = acTab;
        const int* a4 = actb; u64t* a5 = spbuf; u64t* a6 = apbuf;
        h16* a7 = hsrec; h16* a8 = harec;
        void* args[] = {&a0, &a1, &a2, &a3, &a4, &a5, &a6, &a7, &a8};
        hipLaunchCooperativeKernel((const void*)act_scan_k, dim3(512), dim3(256), args, 0, stream);
    }
    gemm_k<3,true><<<dim3(256, 8), dim3(256), 0, stream>>>(h2fW, h2fb, hsrec, tokrec, harec, Xh, nFH, nH);
    loss_k<<<dim3(nS * nB), dim3(128), 0, stream>>>(Xh, f2aW, f2ab, actb, losses);
    reduce_k<<<dim3(1), dim3(256), 0, stream>>>(losses, (float*)d_out);
}

// Round 6
// 4694.596 us; speedup vs baseline: 6.1661x; 1.0249x over previous
//
#include <hip/hip_runtime.h>
#include <math.h>

constexpr int nB = 64, nS = 256, nAc = 256, nH = 512, nG = 2048;
constexpr int nWD = 320, nNA = 75, nLB = 48, nFH = 2560;
constexpr int BH = nB * nH; // 32768

typedef _Float16 h16;
typedef _Float16 h16x8 __attribute__((ext_vector_type(8)));
typedef _Float16 h16x4 __attribute__((ext_vector_type(4)));
typedef _Float16 h16x2 __attribute__((ext_vector_type(2)));
typedef float f32x4 __attribute__((ext_vector_type(4)));
typedef unsigned long long u64t;

__device__ __forceinline__ float sigf(float x) { return 1.0f / (1.0f + __expf(-x)); }

#if __has_builtin(__builtin_amdgcn_fdot2)
#define FDOT2(a, b, c) __builtin_amdgcn_fdot2((a), (b), (c), false)
#else
__device__ __forceinline__ float FDOT2(h16x2 a, h16x2 b, float c) {
    return c + (float)a[0] * (float)b[0] + (float)a[1] * (float)b[1];
}
#endif

// ---------------- init: zero hsrec prefix + transport buffers + counters ----------------
// Transport zeroing each launch kills stale stamps from prior graph replays.
__global__ void init_k(h16* __restrict__ hsrec, int* __restrict__ counts, int* __restrict__ fill,
                       u64t* __restrict__ hbuf, u64t* __restrict__ spbuf, u64t* __restrict__ apbuf)
{
    int i = blockIdx.x * 256 + threadIdx.x;   // grid 256x256 = 65536
    if (i < 2 * BH) hsrec[i] = (h16)0.0f;
    if (i < 32768) { hbuf[i] = 0; spbuf[i] = 0; apbuf[i] = 0; }
    if (i < nLB) { counts[i] = 0; fill[i] = 0; }
}

// ---------------- generic fp32 -> fp16 conversion ----------------
__global__ __launch_bounds__(256)
void cvt_k(const float* __restrict__ src, h16* __restrict__ dst, int n4)
{
    const int i = blockIdx.x * 256 + threadIdx.x;
    if (i < n4) {
        const float4 a = ((const float4*)src)[i];
        h16x4 v; v[0]=(h16)a.x; v[1]=(h16)a.y; v[2]=(h16)a.z; v[3]=(h16)a.w;
        ((h16x4*)dst)[i] = v;
    }
}

// ---------------- embedding gather -> tok fp16 [b][s][0:320] ----------------
__global__ __launch_bounds__(64)
void embed_k(const int* __restrict__ tokb, const int* __restrict__ posb,
             const float* __restrict__ wemb, const float* __restrict__ pemb,
             h16* __restrict__ tok)
{
    const int r = blockIdx.x;            // b*nS + s
    const int tid = threadIdx.x;
    const int tk = tokb[r], pp = posb[r];
    h16x8* d = (h16x8*)(tok + (size_t)r * nWD);
    if (tid < 32) {
        const float4* sw = (const float4*)(wemb + (size_t)tk * 256);
        const float4 a = sw[2 * tid], b = sw[2 * tid + 1];
        h16x8 o;
        o[0]=(h16)a.x; o[1]=(h16)a.y; o[2]=(h16)a.z; o[3]=(h16)a.w;
        o[4]=(h16)b.x; o[5]=(h16)b.y; o[6]=(h16)b.z; o[7]=(h16)b.w;
        d[tid] = o;
    } else if (tid < 40) {
        const int q = tid - 32;
        const float4* sp = (const float4*)(pemb + (size_t)pp * 64);
        const float4 a = sp[2 * q], b = sp[2 * q + 1];
        h16x8 o;
        o[0]=(h16)a.x; o[1]=(h16)a.y; o[2]=(h16)a.z; o[3]=(h16)a.w;
        o[4]=(h16)b.x; o[5]=(h16)b.y; o[6]=(h16)b.z; o[7]=(h16)b.w;
        d[32 + q] = o;
    }
}

// ---------------- action-gate table: acTab[a][j] = aemb[a]·aWih[j] + ab[j] ----------------
__global__ __launch_bounds__(256)
void actab_k(const float* __restrict__ aemb, const float* __restrict__ aWih,
             const float* __restrict__ ab, float* __restrict__ acTab)
{
    const int a = blockIdx.x;            // 0..74
    __shared__ float ae[64];
    const int tid = threadIdx.x;
    if (tid < 64) ae[tid] = aemb[a * 64 + tid];
    __syncthreads();
    for (int j = tid; j < nG; j += 256) {
        const float* wr = aWih + (size_t)j * 64;
        float s = ab[j];
        #pragma unroll
        for (int k = 0; k < 64; k += 4) {
            const float4 w = *(const float4*)(wr + k);
            s = fmaf(w.x, ae[k], s);     s = fmaf(w.y, ae[k + 1], s);
            s = fmaf(w.z, ae[k + 2], s); s = fmaf(w.w, ae[k + 3], s);
        }
        acTab[(size_t)a * nG + j] = s;
    }
}

// =============== MFMA fp16 GEMM: C[r][n] = Arow(r)·Wm[n][:] + bias[n] ===============
// 64x64 tile, 4 waves in 2x2, each wave 2x2 fragments of 16x16, K-step 32.
// MODE 0: A=tok, r=(s*64+b) -> tok[(b*nS+s)*nWD]
// MODE 1: A row r*nH
// MODE 3: A pieces (hsrec+2BH, hsrec+BH, hsrec, tokrec, harec), RELU
// MODE 4: A row r*nWD, epilogue += A1[r*nH+n]
template<int MODE, bool RELU>
__global__ __launch_bounds__(256)
void mgemm_k(const h16* __restrict__ Wm, const float* __restrict__ bias,
             const h16* __restrict__ A0, const h16* __restrict__ A1,
             const h16* __restrict__ A2, h16* __restrict__ C, int Ktot, int ldC)
{
    const int bm = blockIdx.x << 6, bn = blockIdx.y << 6;
    const int tid = threadIdx.x;
    const int lane = tid & 63, wave = tid >> 6;
    const int wr = wave >> 1, wc = wave & 1;
    __shared__ __align__(16) h16 As[64][40];
    __shared__ __align__(16) h16 Ws[64][40];
    const int srow = tid >> 2, sk = (tid & 3) << 3;
    const int r3 = bm + srow;
    const h16* arow = nullptr;
    if (MODE == 0) { const int b = r3 & 63, s = r3 >> 6; arow = A0 + ((size_t)b * nS + s) * nWD; }
    if (MODE == 1) { arow = A0 + (size_t)r3 * nH; }
    if (MODE == 4) { arow = A0 + (size_t)r3 * nWD; }
    const h16* wrow = Wm + (size_t)(bn + srow) * Ktot;
    f32x4 acc[2][2] = {};
    for (int k0 = 0; k0 < Ktot; k0 += 32) {
        h16x8 av, wv;
        if (MODE == 3) {
            const int k = k0 + sk;
            const int p = k >> 9;
            const h16* base = (p == 0) ? A0 + 2 * BH : (p == 1) ? A0 + BH
                            : (p == 2) ? A0 : (p == 3) ? A1 : A2;
            av = *(const h16x8*)(base + (size_t)r3 * nH + (k & 511));
        } else {
            av = *(const h16x8*)(arow + k0 + sk);
        }
        wv = *(const h16x8*)(wrow + k0 + sk);
        __syncthreads();
        *(h16x8*)(&As[srow][sk]) = av;
        *(h16x8*)(&Ws[srow][sk]) = wv;
        __syncthreads();
        const int fk = (lane >> 4) << 3;
        const int fr = lane & 15;
        h16x8 af0 = *(const h16x8*)(&As[(wr << 5) + fr][fk]);
        h16x8 af1 = *(const h16x8*)(&As[(wr << 5) + 16 + fr][fk]);
        h16x8 bf0 = *(const h16x8*)(&Ws[(wc << 5) + fr][fk]);
        h16x8 bf1 = *(const h16x8*)(&Ws[(wc << 5) + 16 + fr][fk]);
        acc[0][0] = __builtin_amdgcn_mfma_f32_16x16x32_f16(af0, bf0, acc[0][0], 0, 0, 0);
        acc[0][1] = __builtin_amdgcn_mfma_f32_16x16x32_f16(af0, bf1, acc[0][1], 0, 0, 0);
        acc[1][0] = __builtin_amdgcn_mfma_f32_16x16x32_f16(af1, bf0, acc[1][0], 0, 0, 0);
        acc[1][1] = __builtin_amdgcn_mfma_f32_16x16x32_f16(af1, bf1, acc[1][1], 0, 0, 0);
    }
    #pragma unroll
    for (int mi = 0; mi < 2; ++mi) {
        #pragma unroll
        for (int ni = 0; ni < 2; ++ni) {
            const int col = bn + (wc << 5) + (ni << 4) + (lane & 15);
            const float bs = bias[col];
            #pragma unroll
            for (int rg = 0; rg < 4; ++rg) {
                const int row = bm + (wr << 5) + (mi << 4) + ((lane >> 4) << 2) + rg;
                float x = acc[mi][ni][rg] + bs;
                if (MODE == 4) x += (float)A1[(size_t)row * nH + col];
                if (RELU) x = fmaxf(x, 0.0f);
                C[(size_t)row * ldC + col] = (h16)x;
            }
        }
    }
}

// ---------------- label sort for red_W batched GEMM ----------------
__global__ void hist_k(const int* __restrict__ actb, int* __restrict__ lab, int* __restrict__ counts)
{
    const int r = blockIdx.x * 256 + threadIdx.x;
    const int t = r >> 6, b = r & 63;
    const int a = actb[b * nAc + t];
    const int l = a % nLB;
    lab[r] = l;
    atomicAdd(&counts[l], 1);
}

__global__ void tiles_k(const int* __restrict__ counts, int* __restrict__ offs,
                        int* __restrict__ tl_lab, int* __restrict__ tl_start,
                        int* __restrict__ tl_cnt, int* __restrict__ ntiles)
{
    if (blockIdx.x == 0 && threadIdx.x == 0) {
        int o = 0, nt = 0;
        for (int l = 0; l < nLB; ++l) {
            offs[l] = o;
            const int c = counts[l];
            for (int s0 = 0; s0 < c; s0 += 64) {
                tl_lab[nt] = l; tl_start[nt] = o + s0; tl_cnt[nt] = min(64, c - s0); ++nt;
            }
            o += c;
        }
        offs[nLB] = o;
        ntiles[0] = nt;
    }
}

__global__ void scatter_k(const int* __restrict__ lab, const int* __restrict__ offs,
                          int* __restrict__ fill, int* __restrict__ idx)
{
    const int r = blockIdx.x * 256 + threadIdx.x;
    const int l = lab[r];
    const int pos = offs[l] + atomicAdd(&fill[l], 1);
    idx[pos] = r;
}

// composed[r][i] = tanh( pair(r)·red_W[l][i][:] + red_b[l][i] ), rows grouped by label
__global__ __launch_bounds__(256)
void comp_gemm_k(const h16* __restrict__ tok, const float* __restrict__ redW,
                 const float* __restrict__ redb, const int* __restrict__ idx,
                 const int* __restrict__ tl_lab, const int* __restrict__ tl_start,
                 const int* __restrict__ tl_cnt, const int* __restrict__ ntiles,
                 h16* __restrict__ comp)
{
    const int tile = blockIdx.x;
    if (tile >= ntiles[0]) return;
    const int cn0 = blockIdx.y << 6;
    const int l = tl_lab[tile], rst = tl_start[tile], mrows = tl_cnt[tile];
    __shared__ int rows_s[64];
    __shared__ __align__(16) float As[16][68];
    __shared__ __align__(16) float Ws[16][68];
    const int tid = threadIdx.x;
    if (tid < 64) rows_s[tid] = (tid < mrows) ? idx[rst + tid] : -1;
    __syncthreads();
    const int alm = tid >> 1, alk = (tid & 1) << 3;
    const int wlm = tid >> 2, wlk = (tid & 3) << 2;
    const int trow = tid >> 4, tcol = tid & 15;
    const int rm = (tid < 128) ? rows_s[alm] : -1;
    const h16* arow0 = tok;
    const h16* arow1 = tok;
    if (rm >= 0) {
        const int b = rm & 63, t = rm >> 6;
        arow0 = tok + ((size_t)b * nS + t) * nWD;
        arow1 = tok + ((size_t)b * nS + max(t - 1, 0)) * nWD;
    }
    const float* wrow = redW + (size_t)l * (320 * 640) + (size_t)(cn0 + wlm) * 640;
    float acc[4][4] = {};
    for (int k0 = 0; k0 < 640; k0 += 16) {
        const int k = k0 + alk;
        h16x8 av = {};
        if (rm >= 0) av = (k < 320) ? *(const h16x8*)(arow0 + k)
                                    : *(const h16x8*)(arow1 + (k - 320));
        const float4 wv = *(const float4*)(wrow + k0 + wlk);
        __syncthreads();
        if (tid < 128) {
            #pragma unroll
            for (int j = 0; j < 8; ++j) As[alk + j][alm] = (float)av[j];
        }
        Ws[wlk + 0][wlm] = wv.x; Ws[wlk + 1][wlm] = wv.y;
        Ws[wlk + 2][wlm] = wv.z; Ws[wlk + 3][wlm] = wv.w;
        __syncthreads();
        #pragma unroll
        for (int kk = 0; kk < 16; ++kk) {
            const float4 a4 = *(const float4*)&As[kk][trow << 2];
            const float4 w4 = *(const float4*)&Ws[kk][tcol << 2];
            const float aa[4] = {a4.x, a4.y, a4.z, a4.w};
            const float ww[4] = {w4.x, w4.y, w4.z, w4.w};
            #pragma unroll
            for (int i = 0; i < 4; ++i)
                #pragma unroll
                for (int j = 0; j < 4; ++j)
                    acc[i][j] = fmaf(aa[i], ww[j], acc[i][j]);
        }
    }
    #pragma unroll
    for (int i = 0; i < 4; ++i) {
        const int rr = rows_s[(trow << 2) + i];
        if (rr < 0) continue;
        #pragma unroll
        for (int j = 0; j < 4; ++j) {
            const int cc = cn0 + (tcol << 2) + j;
            comp[(size_t)rr * nWD + cc] = (h16)tanhf(acc[i][j] + redb[l * nWD + cc]);
        }
    }
}

// =================== scans: stamped-word transport, 1024-thr blocks ===================
// Group = 8 blocks (was 32): per-step transport fan-out /4. Block jb owns h-slice
// [jb*64, jb*64+64) (256 gate rows). Thread (lr=tid&255, ks=tid>>8) does 1 gate row
// x 128-k slice; W register-resident (128 halves = 64 VGPR). Publish u64
// {stamp=t+1, h16x2}; readers poll own 2 words; init zeroes buffers per launch.

// ---------------- token LSTM scan: 64 blocks x 1024 thr ----------------
__global__ __launch_bounds__(1024)
void tok_scan_k(const h16* __restrict__ W16, const h16* __restrict__ gx,
                u64t* __restrict__ hq, h16* __restrict__ tokrec)
{
    const int blk = blockIdx.x;
    const int g = blk >> 3, jb = blk & 7;
    const int tid = threadIdx.x;
    const int lr = tid & 255;            // local gate row
    const int ks = tid >> 8;             // 0..3, k-slice of 128
    const int grow = (lr >> 6) * nH + (jb << 6) + (lr & 63);
    __shared__ __align__(16) h16 hsm[8][nH];     // 8 KB
    __shared__ float ps[4][8][256];              // 32 KB
    __shared__ float gex[256][9];                // 9 KB
    const h16* wrow = W16 + (size_t)grow * nH + (ks << 7);
    h16x8 wreg[16];
    #pragma unroll
    for (int i = 0; i < 16; ++i) wreg[i] = *(const h16x8*)(wrow + (i << 3));
    float creg[2] = {0.0f, 0.0f};
    for (int t = 0; t < nS; ++t) {
        float gp[2];
        #pragma unroll
        for (int u = 0; u < 2; ++u) {
            const int b = ks + (u << 2);
            gp[u] = (float)gx[(size_t)((t << 6) + (g << 3) + b) * nG + grow];
        }
        if (t == 0) {
            ((uint2*)hsm)[tid] = make_uint2(0u, 0u);
        } else {
            const int want = t;
            const size_t base = (size_t)((t - 1) & 1) * 16384 + ((size_t)(g << 3) << 8);
            const int w0 = tid << 1;
            u64t v0 = __hip_atomic_load(hq + base + w0,     __ATOMIC_RELAXED, __HIP_MEMORY_SCOPE_AGENT);
            u64t v1 = __hip_atomic_load(hq + base + w0 + 1, __ATOMIC_RELAXED, __HIP_MEMORY_SCOPE_AGENT);
            while ((int)(v0 >> 32) != want) {
                __builtin_amdgcn_s_sleep(1);
                v0 = __hip_atomic_load(hq + base + w0, __ATOMIC_RELAXED, __HIP_MEMORY_SCOPE_AGENT);
            }
            while ((int)(v1 >> 32) != want) {
                __builtin_amdgcn_s_sleep(1);
                v1 = __hip_atomic_load(hq + base + w0 + 1, __ATOMIC_RELAXED, __HIP_MEMORY_SCOPE_AGENT);
            }
            ((unsigned*)hsm)[w0] = (unsigned)v0;
            ((unsigned*)hsm)[w0 + 1] = (unsigned)v1;
        }
        __syncthreads();
        float acc[8] = {0,0,0,0,0,0,0,0};
        #pragma unroll
        for (int i = 0; i < 16; ++i) {
            const h16x2* wp = (const h16x2*)&wreg[i];
            #pragma unroll
            for (int b = 0; b < 8; ++b) {
                h16x8 hv = *(const h16x8*)(&hsm[b][(ks << 7) + (i << 3)]);
                const h16x2* hp = (const h16x2*)&hv;
                acc[b] = FDOT2(hp[0], wp[0], acc[b]);
                acc[b] = FDOT2(hp[1], wp[1], acc[b]);
                acc[b] = FDOT2(hp[2], wp[2], acc[b]);
                acc[b] = FDOT2(hp[3], wp[3], acc[b]);
            }
        }
        #pragma unroll
        for (int b = 0; b < 8; ++b) ps[ks][b][lr] = acc[b];
        __syncthreads();
        #pragma unroll
        for (int u = 0; u < 2; ++u) {
            const int b = ks + (u << 2);
            float s = gp[u];
            #pragma unroll
            for (int k2 = 0; k2 < 4; ++k2) s += ps[k2][b][lr];
            gex[lr][b] = s;
        }
        __syncthreads();
        if (tid < 256) {
            const int q = tid >> 3, b2 = tid & 7;   // j-pair q: local j = 2q,2q+1
            float hn[2];
            #pragma unroll
            for (int u = 0; u < 2; ++u) {
                const int j = (q << 1) + u;
                const float gi = gex[j][b2], gf = gex[64 + j][b2];
                const float gg = gex[128 + j][b2], go = gex[192 + j][b2];
                const float cn = sigf(gf) * creg[u] + sigf(gi) * tanhf(gg);
                hn[u] = sigf(go) * tanhf(cn);
                creg[u] = cn;
            }
            const int bg = (g << 3) + b2;
            h16x2 hp2; hp2[0] = (h16)hn[0]; hp2[1] = (h16)hn[1];
            const unsigned pay = __builtin_bit_cast(unsigned, hp2);
            const u64t word = ((u64t)(unsigned)(t + 1) << 32) | pay;
            __hip_atomic_store(hq + (size_t)(t & 1) * 16384 + ((size_t)bg << 8) + (jb << 5) + q,
                               word, __ATOMIC_RELAXED, __HIP_MEMORY_SCOPE_AGENT);
            *(h16x2*)(tokrec + (size_t)t * BH + (size_t)bg * nH + (jb << 6) + (q << 1)) = hp2;
        }
    }
}

// ---------------- action scan: 128 blocks x 1024 thr (2 roles) ----------------
__global__ __launch_bounds__(1024)
void act_scan_k(const h16* __restrict__ sW16, const h16* __restrict__ aW16,
                const h16* __restrict__ stX, const float* __restrict__ acTab,
                const int* __restrict__ actb,
                u64t* __restrict__ sq, u64t* __restrict__ aq,
                h16* __restrict__ hsrec, h16* __restrict__ harec)
{
    const int blk = blockIdx.x;
    const int role = blk >> 6;
    const int sub = blk & 63;
    const int g = sub >> 3, jb = sub & 7;
    const int tid = threadIdx.x;
    const int lr = tid & 255;
    const int ks = tid >> 8;
    const int grow = (lr >> 6) * nH + (jb << 6) + (lr & 63);
    const h16* W16 = role ? aW16 : sW16;
    u64t* hq = role ? aq : sq;
    __shared__ __align__(16) h16 hsm[8][nH];
    __shared__ float ps[4][8][256];
    __shared__ float gex[256][9];
    const h16* wrow = W16 + (size_t)grow * nH + (ks << 7);
    h16x8 wreg[16];
    #pragma unroll
    for (int i = 0; i < 16; ++i) wreg[i] = *(const h16x8*)(wrow + (i << 3));
    float creg[2] = {0.0f, 0.0f};
    for (int t = 0; t < nAc; ++t) {
        float gp[2];
        #pragma unroll
        for (int u = 0; u < 2; ++u) {
            const int b = ks + (u << 2);
            if (role) {
                const int a = actb[((g << 3) + b) * nAc + t];
                gp[u] = acTab[(size_t)a * nG + grow];
            } else {
                gp[u] = (float)stX[(size_t)((t << 6) + (g << 3) + b) * nG + grow];
            }
        }
        if (t == 0) {
            ((uint2*)hsm)[tid] = make_uint2(0u, 0u);
        } else {
            const int want = t;
            const size_t base = (size_t)((t - 1) & 1) * 16384 + ((size_t)(g << 3) << 8);
            const int w0 = tid << 1;
            u64t v0 = __hip_atomic_load(hq + base + w0,     __ATOMIC_RELAXED, __HIP_MEMORY_SCOPE_AGENT);
            u64t v1 = __hip_atomic_load(hq + base + w0 + 1, __ATOMIC_RELAXED, __HIP_MEMORY_SCOPE_AGENT);
            while ((int)(v0 >> 32) != want) {
                __builtin_amdgcn_s_sleep(1);
                v0 = __hip_atomic_load(hq + base + w0, __ATOMIC_RELAXED, __HIP_MEMORY_SCOPE_AGENT);
            }
            while ((int)(v1 >> 32) != want) {
                __builtin_amdgcn_s_sleep(1);
                v1 = __hip_atomic_load(hq + base + w0 + 1, __ATOMIC_RELAXED, __HIP_MEMORY_SCOPE_AGENT);
            }
            ((unsigned*)hsm)[w0] = (unsigned)v0;
            ((unsigned*)hsm)[w0 + 1] = (unsigned)v1;
        }
        __syncthreads();
        float acc[8] = {0,0,0,0,0,0,0,0};
        #pragma unroll
        for (int i = 0; i < 16; ++i) {
            const h16x2* wp = (const h16x2*)&wreg[i];
            #pragma unroll
            for (int b = 0; b < 8; ++b) {
                h16x8 hv = *(const h16x8*)(&hsm[b][(ks << 7) + (i << 3)]);
                const h16x2* hp = (const h16x2*)&hv;
                acc[b] = FDOT2(hp[0], wp[0], acc[b]);
                acc[b] = FDOT2(hp[1], wp[1], acc[b]);
                acc[b] = FDOT2(hp[2], wp[2], acc[b]);
                acc[b] = FDOT2(hp[3], wp[3], acc[b]);
            }
        }
        #pragma unroll
        for (int b = 0; b < 8; ++b) ps[ks][b][lr] = acc[b];
        __syncthreads();
        #pragma unroll
        for (int u = 0; u < 2; ++u) {
            const int b = ks + (u << 2);
            float s = gp[u];
            #pragma unroll
            for (int k2 = 0; k2 < 4; ++k2) s += ps[k2][b][lr];
            gex[lr][b] = s;
        }
        __syncthreads();
        if (tid < 256) {
            const int q = tid >> 3, b2 = tid & 7;
            float hn[2];
            #pragma unroll
            for (int u = 0; u < 2; ++u) {
                const int j = (q << 1) + u;
                const float gi = gex[j][b2], gf = gex[64 + j][b2];
                const float gg = gex[128 + j][b2], go = gex[192 + j][b2];
                const float cn = sigf(gf) * creg[u] + sigf(gi) * tanhf(gg);
                hn[u] = sigf(go) * tanhf(cn);
                creg[u] = cn;
            }
            const int bg = (g << 3) + b2;
            h16x2 hp2; hp2[0] = (h16)hn[0]; hp2[1] = (h16)hn[1];
            const unsigned pay = __builtin_bit_cast(unsigned, hp2);
            const u64t word = ((u64t)(unsigned)(t + 1) << 32) | pay;
            __hip_atomic_store(hq + (size_t)(t & 1) * 16384 + ((size_t)bg << 8) + (jb << 5) + q,
                               word, __ATOMIC_RELAXED, __HIP_MEMORY_SCOPE_AGENT);
            h16* rec = role ? (harec + (size_t)t * BH) : (hsrec + (size_t)(t + 2) * BH);
            *(h16x2*)(rec + (size_t)bg * nH + (jb << 6) + (q << 1)) = hp2;
        }
    }
}

// ---------------- per-(t,b) logits + log-softmax loss ----------------
__global__ __launch_bounds__(128)
void loss_k(const h16* __restrict__ hidden, const float* __restrict__ f2aW,
            const float* __restrict__ f2ab, const int* __restrict__ actb,
            float* __restrict__ losses)
{
    const int r = blockIdx.x;
    const int t = r >> 6, b = r & 63;
    __shared__ __align__(16) float hrow[nH];
    __shared__ float lg[nNA + 1];
    const int tid = threadIdx.x;
    if (tid < 64) {
        const h16x8 v = ((const h16x8*)(hidden + (size_t)r * nH))[tid];
        #pragma unroll
        for (int j = 0; j < 8; ++j) hrow[tid * 8 + j] = (float)v[j];
    }
    __syncthreads();
    if (tid < nNA) {
        const float* wr = f2aW + (size_t)tid * nH;
        float a = f2ab[tid];
        for (int k = 0; k < nH; k += 4) {
            const float4 wv = *(const float4*)(wr + k);
            const float4 hv = *(const float4*)(&hrow[k]);
            a = fmaf(wv.x, hv.x, a); a = fmaf(wv.y, hv.y, a);
            a = fmaf(wv.z, hv.z, a); a = fmaf(wv.w, hv.w, a);
        }
        lg[tid] = a;
    }
    __syncthreads();
    if (tid < 64) {
        float m = -1e30f;
        for (int i = tid; i < nNA; i += 64) m = fmaxf(m, lg[i]);
        #pragma unroll
        for (int o = 32; o > 0; o >>= 1) m = fmaxf(m, __shfl_xor(m, o));
        float s = 0.0f;
        for (int i = tid; i < nNA; i += 64) s += __expf(lg[i] - m);
        #pragma unroll
        for (int o = 32; o > 0; o >>= 1) s += __shfl_xor(s, o);
        if (tid == 0) {
            const int a = actb[b * nAc + t];
            losses[r] = m + logf(s) - lg[a];
        }
    }
}

__global__ __launch_bounds__(256)
void reduce_k(const float* __restrict__ losses, float* __restrict__ out)
{
    __shared__ float sm[256];
    const int tid = threadIdx.x;
    float a = 0.0f;
    for (int i = tid; i < nS * nB; i += 256) a += losses[i];
    sm[tid] = a; __syncthreads();
    for (int s = 128; s > 0; s >>= 1) { if (tid < s) sm[tid] += sm[tid + s]; __syncthreads(); }
    if (tid == 0) out[0] = sm[0] * (1.0f / 16384.0f);
}

// ---------------- launch ----------------
extern "C" void kernel_launch(void* const* d_in, const int* in_sizes, int n_in,
                              void* d_out, int out_size, void* d_ws, size_t ws_size,
                              hipStream_t stream)
{
    const int*   tokb  = (const int*)  d_in[0];
    const int*   posb  = (const int*)  d_in[1];
    const int*   actb  = (const int*)  d_in[3];
    const float* wemb  = (const float*)d_in[4];
    const float* pemb  = (const float*)d_in[5];
    const float* aemb  = (const float*)d_in[6];
    const float* tWih  = (const float*)d_in[7];
    const float* tWhh  = (const float*)d_in[8];
    const float* tb    = (const float*)d_in[9];
    const float* sWih  = (const float*)d_in[10];
    const float* sWhh  = (const float*)d_in[11];
    const float* sb    = (const float*)d_in[12];
    const float* aWih  = (const float*)d_in[13];
    const float* aWhh  = (const float*)d_in[14];
    const float* ab    = (const float*)d_in[15];
    const float* redW  = (const float*)d_in[16];
    const float* redb  = (const float*)d_in[17];
    const float* compW = (const float*)d_in[18];
    const float* compb = (const float*)d_in[19];
    const float* h2fW  = (const float*)d_in[20];
    const float* h2fb  = (const float*)d_in[21];
    const float* f2aW  = (const float*)d_in[22];
    const float* f2ab  = (const float*)d_in[23];

    // ---- workspace carve ----
    char* base = (char*)d_ws;
    auto carve = [&](size_t bytes) { char* p = base; base += (bytes + 255) & ~(size_t)255; return p; };
    h16*   tok    = (h16*)  carve((size_t)nB * nS * nWD * 2);
    h16*   Xh     = (h16*)  carve((size_t)nS * nB * nG * 2);
    h16*   comph  = (h16*)  carve((size_t)nS * nB * nWD * 2);
    h16*   stinh  = (h16*)  carve((size_t)nS * BH * 2);
    h16*   tokrec = (h16*)  carve((size_t)nS * BH * 2);
    h16*   hsrec  = (h16*)  carve((size_t)(nS + 2) * BH * 2);
    h16*   harec  = (h16*)  carve((size_t)nS * BH * 2);
    h16*   tW16   = (h16*)  carve((size_t)nG * nH * 2);     // tok Whh
    h16*   sW16   = (h16*)  carve((size_t)nG * nH * 2);     // st Whh
    h16*   aW16   = (h16*)  carve((size_t)nG * nH * 2);     // ac Whh
    h16*   tWih16 = (h16*)  carve((size_t)nG * nWD * 2);    // tok Wih
    h16*   sWih16 = (h16*)  carve((size_t)nG * nH * 2);     // st Wih
    h16*   h2f16  = (h16*)  carve((size_t)nH * nFH * 2);    // h2f W
    h16*   comp16 = (h16*)  carve((size_t)nH * nWD * 2);    // comp W
    float* acTab  = (float*)carve((size_t)nNA * nG * 4);
    u64t*  hbuf   = (u64t*) carve((size_t)2 * 16384 * 8);
    u64t*  spbuf  = (u64t*) carve((size_t)2 * 16384 * 8);
    u64t*  apbuf  = (u64t*) carve((size_t)2 * 16384 * 8);
    float* losses = (float*)carve((size_t)nS * nB * 4);
    int*   lab      = (int*)carve((size_t)nS * nB * 4);
    int*   counts   = (int*)carve(nLB * 4);
    int*   offs     = (int*)carve((nLB + 1) * 4);
    int*   fill     = (int*)carve(nLB * 4);
    int*   tl_lab   = (int*)carve(320 * 4);
    int*   tl_start = (int*)carve(320 * 4);
    int*   tl_cnt   = (int*)carve(320 * 4);
    int*   ntiles   = (int*)carve(4);
    int*   idxb     = (int*)carve((size_t)nS * nB * 4);

    init_k<<<dim3(256), dim3(256), 0, stream>>>(hsrec, counts, fill, hbuf, spbuf, apbuf);
    embed_k<<<dim3(nB * nS), dim3(64), 0, stream>>>(tokb, posb, wemb, pemb, tok);
    actab_k<<<dim3(nNA), dim3(256), 0, stream>>>(aemb, aWih, ab, acTab);
    cvt_k<<<dim3(1024), dim3(256), 0, stream>>>(tWhh, tW16, 262144);
    cvt_k<<<dim3(1024), dim3(256), 0, stream>>>(sWhh, sW16, 262144);
    cvt_k<<<dim3(1024), dim3(256), 0, stream>>>(aWhh, aW16, 262144);
    cvt_k<<<dim3(640),  dim3(256), 0, stream>>>(tWih, tWih16, 163840);
    cvt_k<<<dim3(1024), dim3(256), 0, stream>>>(sWih, sWih16, 262144);
    cvt_k<<<dim3(1280), dim3(256), 0, stream>>>(h2fW, h2f16, 327680);
    cvt_k<<<dim3(160),  dim3(256), 0, stream>>>(compW, comp16, 40960);
    // tokX = tok @ tok_Wih.T + tok_b -> Xh (MFMA)
    mgemm_k<0,false><<<dim3(256, 32), dim3(256), 0, stream>>>(tWih16, tb, tok, nullptr, nullptr, Xh, nWD, nG);
    hist_k<<<dim3(64), dim3(256), 0, stream>>>(actb, lab, counts);
    tiles_k<<<dim3(1), dim3(64), 0, stream>>>(counts, offs, tl_lab, tl_start, tl_cnt, ntiles);
    scatter_k<<<dim3(64), dim3(256), 0, stream>>>(lab, offs, fill, idxb);
    comp_gemm_k<<<dim3(304, 5), dim3(256), 0, stream>>>(tok, redW, redb, idxb, tl_lab, tl_start, tl_cnt, ntiles, comph);
    // token scan (cooperative for co-residency)
    {
        const h16* a0 = tW16; const h16* a1 = Xh; u64t* a2 = hbuf; h16* a3 = tokrec;
        void* args[] = {&a0, &a1, &a2, &a3};
        hipLaunchCooperativeKernel((const void*)tok_scan_k, dim3(64), dim3(1024), args, 0, stream);
    }
    // st_in = tokrec + composed @ comp_W.T + comp_b -> stinh (MFMA)
    mgemm_k<4,false><<<dim3(256, 8), dim3(256), 0, stream>>>(comp16, compb, comph, tokrec, nullptr, stinh, nWD, nH);
    // stX = st_in @ st_Wih.T + st_b -> Xh (MFMA)
    mgemm_k<1,false><<<dim3(256, 32), dim3(256), 0, stream>>>(sWih16, sb, stinh, nullptr, nullptr, Xh, nH, nG);
    // action scan (cooperative): both chains concurrently
    {
        const h16* a0 = sW16; const h16* a1 = aW16; const h16* a2 = Xh; const float* a3 = acTab;
        const int* a4 = actb; u64t* a5 = spbuf; u64t* a6 = apbuf;
        h16* a7 = hsrec; h16* a8 = harec;
        void* args[] = {&a0, &a1, &a2, &a3, &a4, &a5, &a6, &a7, &a8};
        hipLaunchCooperativeKernel((const void*)act_scan_k, dim3(128), dim3(1024), args, 0, stream);
    }
    // hidden = relu(feat @ h2f_W.T + h2f_b) -> Xh (MFMA)
    mgemm_k<3,true><<<dim3(256, 8), dim3(256), 0, stream>>>(h2f16, h2fb, hsrec, tokrec, harec, Xh, nFH, nH);
    loss_k<<<dim3(nS * nB), dim3(128), 0, stream>>>(Xh, f2aW, f2ab, actb, losses);
    reduce_k<<<dim3(1), dim3(256), 0, stream>>>(losses, (float*)d_out);
}